// Round 7
// baseline (379.251 us; speedup 1.0000x reference)
//
#include <hip/hip_runtime.h>
#include <hip/hip_bf16.h>

#define B_ 32
#define T_ 64
#define H_ 128
#define L3OUT 54
#define FLAT_ 1728

typedef __attribute__((ext_vector_type(8))) short bf16x8;
typedef __attribute__((ext_vector_type(4))) float f32x4;

__device__ __forceinline__ float leakyf(float v) { return v > 0.f ? v : 0.01f * v; }
__device__ __forceinline__ float sigmoidf_(float v) { return 1.f / (1.f + expf(-v)); }
__device__ __forceinline__ unsigned int bf16rne(float v) {
  unsigned int b = __float_as_uint(v);
  return (b + 0x7FFFu + ((b >> 16) & 1u)) >> 16;
}
__device__ __forceinline__ bf16x8 ldb8(const unsigned short* p) {
  return *(const bf16x8*)p;
}

// ---------------------------------------------------------------------------
// Kernel 0: weight prep + transposes. 1803 blocks x 256 = 461,568 threads.
// Ranges: w2 split (20480) | w3 split (5120) | linw split (172800) |
// wih0 split, k-padded to 128 (65536) | w1e split, taps padded to 8 (1024) |
// 3 fp32 transposes [512x128]->[128x512] (196608).
// ---------------------------------------------------------------------------
__global__ __launch_bounds__(256) void k_prep(
    const float* __restrict__ w1, const float* __restrict__ w2,
    const float* __restrict__ w3, const float* __restrict__ linw,
    const float* __restrict__ wih0, const float* __restrict__ whh0,
    const float* __restrict__ wih1, const float* __restrict__ whh1,
    unsigned short* __restrict__ w1eh, unsigned short* __restrict__ w1el,
    unsigned short* __restrict__ w2h, unsigned short* __restrict__ w2l,
    unsigned short* __restrict__ w3h, unsigned short* __restrict__ w3l,
    unsigned short* __restrict__ linwh, unsigned short* __restrict__ linwl,
    unsigned short* __restrict__ wih0h, unsigned short* __restrict__ wih0l,
    float* __restrict__ whh0T, float* __restrict__ wih1T,
    float* __restrict__ whh1T) {
  const int e = blockIdx.x * 256 + threadIdx.x;
  if (e >= 264960) {
    int e5 = e - 264960;
    int m = e5 >> 16, r = e5 & 65535;
    int k = r >> 9, j = r & 511;
    const float* src = (m == 0) ? whh0 : ((m == 1) ? wih1 : whh1);
    float* dst = (m == 0) ? whh0T : ((m == 1) ? wih1T : whh1T);
    dst[r] = src[j * 128 + k];
    return;
  }
  float v;
  unsigned short* dh;
  unsigned short* dl;
  int di;
  if (e < 20480) {
    int cc = e / 5120, rem = e - cc * 5120;
    int c2 = rem / 160, r = rem - c2 * 160;
    int tap = r >> 5, c1l = r & 31;
    v = w2[c2 * 640 + (cc * 32 + c1l) * 5 + tap];
    dh = w2h; dl = w2l; di = e;
  } else if (e < 25600) {
    int e2 = e - 20480;
    int c3 = e2 / 160, r = e2 - c3 * 160;
    int tap = r >> 5, c2 = r & 31;
    v = w3[c3 * 160 + c2 * 5 + tap];
    dh = w3h; dl = w3l; di = e2;
  } else if (e < 198400) {
    int e3 = e - 25600;
    v = linw[e3];
    dh = linwh; dl = linwl; di = e3;
  } else if (e < 263936) {
    int e4 = e - 198400;
    int g = e4 >> 7, k = e4 & 127;
    v = (k < 100) ? wih0[g * 100 + k] : 0.f;
    dh = wih0h; dl = wih0l; di = e4;
  } else {
    int i = e - 263936;  // 1024: [c1 128][j 8]
    int c1 = i >> 3, j = i & 7;
    v = (j < 5) ? w1[c1 * 5 + j] : 0.f;
    dh = w1eh; dl = w1el; di = i;
  }
  unsigned int hb = bf16rne(v);
  float hf = __uint_as_float(hb << 16);
  unsigned int lb = bf16rne(v - hf);
  dh[di] = (unsigned short)hb;
  dl[di] = (unsigned short)lb;
}

// ---------------------------------------------------------------------------
// Kernel 1: conv1 + conv2 + conv3, all on MFMA. One block per n, 256 thr.
// Phase A: X -> Xwin[512][8] bf16 hi/lo in LDS (one row per conv1 position,
//   taps 0..7, taps>=5 zero; window = contiguous 8 floats at X[3*pos]).
// Per c1-chunk (32): conv1 MFMA (A=w1e global, B=Xwin LDS, K=32 with 5 used,
//   3 hi/lo passes) -> leaky -> bf16 -> AhU[pos][c1-pairs] (ds_write_b64),
//   then conv2 MFMA (verified round-5/6 structure).
// Then conv3 MFMA via A3 (aliases AhU) -> s3g bf16.
// LDS = 8192*2 + 42560 = 58,944 B -> 2 blocks/CU.
// ---------------------------------------------------------------------------
__global__ __launch_bounds__(256) void k_conv123(
    const float* __restrict__ X,
    const unsigned short* __restrict__ w1eh, const unsigned short* __restrict__ w1el,
    const unsigned short* __restrict__ w2h, const unsigned short* __restrict__ w2l,
    const unsigned short* __restrict__ w3h, const unsigned short* __restrict__ w3l,
    unsigned short* __restrict__ s3g) {
  __shared__ __align__(16) unsigned short Xwh[4096];  // [512 pos][8 taps]
  __shared__ __align__(16) unsigned short Xwl[4096];
  __shared__ __align__(16) unsigned int AhU[10640];   // [532 rows][20 u32]

  const int n = blockIdx.x;
  const int tid = threadIdx.x;
  const int lane = tid & 63;
  const int w = tid >> 6;
  const int l15 = lane & 15;
  const int cg = lane >> 4;

  // zero AhU pad rows 512..531 (conv2 reads them for discarded l2 cols)
  for (int i = tid; i < 400; i += 256) AhU[10240 + i] = 0u;

  // Phase A: build Xwin hi/lo (u32 = 2 taps per write)
  const float* Xn = X + (size_t)n * 1500;
  for (int i = tid; i < 2048; i += 256) {
    int pos = i >> 2, jp = i & 3;
    int s0 = 3 * pos + 2 * jp;
    float v0 = (s0 < 1500) ? Xn[s0] : 0.f;
    float v1 = (s0 + 1 < 1500) ? Xn[s0 + 1] : 0.f;
    unsigned int h0 = bf16rne(v0), h1 = bf16rne(v1);
    float f0 = __uint_as_float(h0 << 16), f1 = __uint_as_float(h1 << 16);
    unsigned int lo0 = bf16rne(v0 - f0), lo1 = bf16rne(v1 - f1);
    ((unsigned int*)Xwh)[i] = h0 | (h1 << 16);
    ((unsigned int*)Xwl)[i] = lo0 | (lo1 << 16);
  }
  __syncthreads();

  const bf16x8 zf = (bf16x8){0, 0, 0, 0, 0, 0, 0, 0};
  f32x4 acc2[3][2];
#pragma unroll
  for (int a = 0; a < 3; ++a)
#pragma unroll
    for (int m = 0; m < 2; ++m) acc2[a][m] = (f32x4){0.f, 0.f, 0.f, 0.f};

  for (int cc = 0; cc < 4; ++cc) {  // 4 chunks of 32 c1
    // ---- conv1 MFMA: 2 m-tiles x 8 n-tiles (this wave) x 3 passes ----
    bf16x8 afh0 = zf, afh1 = zf, afl0 = zf, afl1 = zf;
    if (cg == 0) {
      afh0 = ldb8(w1eh + ((cc * 2 + 0) * 16 + l15) * 8);
      afh1 = ldb8(w1eh + ((cc * 2 + 1) * 16 + l15) * 8);
      afl0 = ldb8(w1el + ((cc * 2 + 0) * 16 + l15) * 8);
      afl1 = ldb8(w1el + ((cc * 2 + 1) * 16 + l15) * 8);
    }
    f32x4 a1[2][8];
#pragma unroll
    for (int m = 0; m < 2; ++m)
#pragma unroll
      for (int q = 0; q < 8; ++q) a1[m][q] = (f32x4){0.f, 0.f, 0.f, 0.f};
#pragma unroll
    for (int nt8 = 0; nt8 < 8; ++nt8) {
      int nt = w * 8 + nt8;
      bf16x8 bh = zf, bl = zf;
      if (cg == 0) {
        bh = ldb8(Xwh + (nt * 16 + l15) * 8);
        bl = ldb8(Xwl + (nt * 16 + l15) * 8);
      }
      a1[0][nt8] = __builtin_amdgcn_mfma_f32_16x16x32_bf16(afh0, bh, a1[0][nt8], 0, 0, 0);
      a1[0][nt8] = __builtin_amdgcn_mfma_f32_16x16x32_bf16(afl0, bh, a1[0][nt8], 0, 0, 0);
      a1[0][nt8] = __builtin_amdgcn_mfma_f32_16x16x32_bf16(afh0, bl, a1[0][nt8], 0, 0, 0);
      a1[1][nt8] = __builtin_amdgcn_mfma_f32_16x16x32_bf16(afh1, bh, a1[1][nt8], 0, 0, 0);
      a1[1][nt8] = __builtin_amdgcn_mfma_f32_16x16x32_bf16(afl1, bh, a1[1][nt8], 0, 0, 0);
      a1[1][nt8] = __builtin_amdgcn_mfma_f32_16x16x32_bf16(afh1, bl, a1[1][nt8], 0, 0, 0);
    }
    __syncthreads();  // previous chunk's conv2 reads of AhU are done
    // ---- epilogue: leaky + bf16 pack -> AhU[pos][pair] (b64 writes) ----
#pragma unroll
    for (int nt8 = 0; nt8 < 8; ++nt8) {
      int pos = (w * 8 + nt8) * 16 + l15;  // C/D: col=lane&15
#pragma unroll
      for (int mt2 = 0; mt2 < 2; ++mt2) {
        float e0 = leakyf(a1[mt2][nt8][0]);
        float e1 = leakyf(a1[mt2][nt8][1]);
        float e2 = leakyf(a1[mt2][nt8][2]);
        float e3 = leakyf(a1[mt2][nt8][3]);
        uint2 pk;
        pk.x = bf16rne(e0) | (bf16rne(e1) << 16);
        pk.y = bf16rne(e2) | (bf16rne(e3) << 16);
        *(uint2*)(&AhU[pos * 20 + mt2 * 8 + cg * 2]) = pk;
      }
    }
    __syncthreads();
    // ---- conv2 MFMA over this chunk (K=32 c1 per tap) ----
    const unsigned short* w2hB = w2h + cc * 5120;
    const unsigned short* w2lB = w2l + cc * 5120;
#pragma unroll
    for (int tap = 0; tap < 5; ++tap) {
      const int wc = tap * 32 + cg * 8;
      bf16x8 ah0 = ldb8(w2hB + l15 * 160 + wc);
      bf16x8 ah1 = ldb8(w2hB + (l15 + 16) * 160 + wc);
      bf16x8 al0 = ldb8(w2lB + l15 * 160 + wc);
      bf16x8 al1 = ldb8(w2lB + (l15 + 16) * 160 + wc);
#pragma unroll
      for (int nti = 0; nti < 3; ++nti) {
        int nt = w + 4 * nti;
        if (nt < 11) {
          bf16x8 bfr = ldb8((const unsigned short*)AhU + (3 * (nt * 16 + l15) + tap) * 40 + cg * 8);
          acc2[nti][0] = __builtin_amdgcn_mfma_f32_16x16x32_bf16(ah0, bfr, acc2[nti][0], 0, 0, 0);
          acc2[nti][0] = __builtin_amdgcn_mfma_f32_16x16x32_bf16(al0, bfr, acc2[nti][0], 0, 0, 0);
          acc2[nti][1] = __builtin_amdgcn_mfma_f32_16x16x32_bf16(ah1, bfr, acc2[nti][1], 0, 0, 0);
          acc2[nti][1] = __builtin_amdgcn_mfma_f32_16x16x32_bf16(al1, bfr, acc2[nti][1], 0, 0, 0);
        }
      }
    }
  }
  __syncthreads();  // all conv2 MFMA reads of AhU done
  // A3 (aliases AhU): rows = l2 (0..195), 16 u32 of c2-pairs; zero pad rows
  for (int i = tid; i < 400; i += 256) AhU[176 * 20 + i] = 0u;
#pragma unroll
  for (int nti = 0; nti < 3; ++nti) {
    int nt = w + 4 * nti;
    if (nt < 11) {
      int l2 = nt * 16 + l15;
#pragma unroll
      for (int mt = 0; mt < 2; ++mt) {
#pragma unroll
        for (int j = 0; j < 2; ++j) {
          float e0 = leakyf(acc2[nti][mt][2 * j]);
          float e1 = leakyf(acc2[nti][mt][2 * j + 1]);
          AhU[l2 * 20 + mt * 8 + cg * 2 + j] = bf16rne(e0) | (bf16rne(e1) << 16);
        }
      }
    }
  }
  __syncthreads();
  // conv3 MFMA: wave w = n-tile (l3 = w*16+l15), M=32 c3 (2 m-tiles)
  f32x4 a3[2];
  a3[0] = (f32x4){0.f, 0.f, 0.f, 0.f};
  a3[1] = (f32x4){0.f, 0.f, 0.f, 0.f};
#pragma unroll
  for (int tap = 0; tap < 5; ++tap) {
    const int wc = tap * 32 + cg * 8;
    bf16x8 wh0 = ldb8(w3h + l15 * 160 + wc);
    bf16x8 wh1 = ldb8(w3h + (l15 + 16) * 160 + wc);
    bf16x8 wl0 = ldb8(w3l + l15 * 160 + wc);
    bf16x8 wl1 = ldb8(w3l + (l15 + 16) * 160 + wc);
    bf16x8 bfr = ldb8((const unsigned short*)AhU + (3 * (w * 16 + l15) + tap) * 40 + cg * 8);
    a3[0] = __builtin_amdgcn_mfma_f32_16x16x32_bf16(wh0, bfr, a3[0], 0, 0, 0);
    a3[0] = __builtin_amdgcn_mfma_f32_16x16x32_bf16(wl0, bfr, a3[0], 0, 0, 0);
    a3[1] = __builtin_amdgcn_mfma_f32_16x16x32_bf16(wh1, bfr, a3[1], 0, 0, 0);
    a3[1] = __builtin_amdgcn_mfma_f32_16x16x32_bf16(wl1, bfr, a3[1], 0, 0, 0);
  }
  int l3 = w * 16 + l15;
  if (l3 < L3OUT) {
#pragma unroll
    for (int mt = 0; mt < 2; ++mt) {
#pragma unroll
      for (int r = 0; r < 4; ++r) {
        int c3 = mt * 16 + cg * 4 + r;
        s3g[(size_t)n * FLAT_ + c3 * L3OUT + l3] = (unsigned short)bf16rne(leakyf(a3[mt][r]));
      }
    }
  }
}

// ---------------------------------------------------------------------------
// Kernel 2: GEMM-1  fe[2048][112] = s3g[2048][1728] @ linw-hl^T. (unchanged)
// ---------------------------------------------------------------------------
__global__ __launch_bounds__(512) void k_gemm_fe(
    const unsigned short* __restrict__ s3g,
    const unsigned short* __restrict__ linwh, const unsigned short* __restrict__ linwl,
    unsigned short* __restrict__ feh, unsigned short* __restrict__ fel) {
  __shared__ __align__(16) unsigned short As[32 * 72];
  __shared__ __align__(16) unsigned short Bh[112 * 72];
  __shared__ __align__(16) unsigned short Bl[112 * 72];

  const int m0 = blockIdx.x * 32;
  const int tid = threadIdx.x;
  const int lane = tid & 63;
  const int w = tid >> 6;
  const int l15 = lane & 15;
  const int cg = lane >> 4;
  const int mi = w & 1;
  const int nh = w >> 1;

  f32x4 acc0 = (f32x4){0.f, 0.f, 0.f, 0.f};
  f32x4 acc1 = (f32x4){0.f, 0.f, 0.f, 0.f};

  for (int kc = 0; kc < 27; ++kc) {
    const int k0 = kc * 64;
    __syncthreads();
    if (tid < 256) {
      int r = tid >> 3, s = tid & 7;
      *(bf16x8*)(As + r * 72 + s * 8) = ldb8(s3g + (size_t)(m0 + r) * FLAT_ + k0 + s * 8);
    }
    for (int i = tid; i < 1792; i += 512) {
      int arr = i / 896, j = i - arr * 896;
      int r = j >> 3, s = j & 7;
      bf16x8 v = (bf16x8){0, 0, 0, 0, 0, 0, 0, 0};
      if (r < 100) v = ldb8((arr ? linwl : linwh) + (size_t)r * FLAT_ + k0 + s * 8);
      *(bf16x8*)((arr ? Bl : Bh) + r * 72 + s * 8) = v;
    }
    __syncthreads();
#pragma unroll
    for (int ks = 0; ks < 2; ++ks) {
      bf16x8 af = ldb8(As + (mi * 16 + l15) * 72 + ks * 32 + cg * 8);
      bf16x8 b0h = ldb8(Bh + (nh * 16 + l15) * 72 + ks * 32 + cg * 8);
      bf16x8 b0l = ldb8(Bl + (nh * 16 + l15) * 72 + ks * 32 + cg * 8);
      acc0 = __builtin_amdgcn_mfma_f32_16x16x32_bf16(af, b0h, acc0, 0, 0, 0);
      acc0 = __builtin_amdgcn_mfma_f32_16x16x32_bf16(af, b0l, acc0, 0, 0, 0);
      if (nh < 3) {
        bf16x8 b1h = ldb8(Bh + ((nh + 4) * 16 + l15) * 72 + ks * 32 + cg * 8);
        bf16x8 b1l = ldb8(Bl + ((nh + 4) * 16 + l15) * 72 + ks * 32 + cg * 8);
        acc1 = __builtin_amdgcn_mfma_f32_16x16x32_bf16(af, b1h, acc1, 0, 0, 0);
        acc1 = __builtin_amdgcn_mfma_f32_16x16x32_bf16(af, b1l, acc1, 0, 0, 0);
      }
    }
  }
  const int sample = m0 + mi * 16 + cg * 4;
#pragma unroll
  for (int t = 0; t < 2; ++t) {
    if (t == 1 && nh >= 3) break;
    int jcol = (nh + 4 * t) * 16 + l15;
    f32x4 av = t ? acc1 : acc0;
#pragma unroll
    for (int r = 0; r < 4; ++r) {
      float v = av[r];
      unsigned int hb = bf16rne(v);
      float hf = __uint_as_float(hb << 16);
      unsigned int lb = bf16rne(v - hf);
      feh[(size_t)(sample + r) * 128 + jcol] = (unsigned short)hb;
      fel[(size_t)(sample + r) * 128 + jcol] = (unsigned short)lb;
    }
  }
}

// ---------------------------------------------------------------------------
// Kernel 3: GEMM-2  xg0 = fe-hl @ wih0-hl^T. (unchanged)
// ---------------------------------------------------------------------------
__global__ __launch_bounds__(256) void k_gemm_xg0(
    const unsigned short* __restrict__ feh, const unsigned short* __restrict__ fel,
    const unsigned short* __restrict__ wih0h, const unsigned short* __restrict__ wih0l,
    float* __restrict__ xg0) {
  const int m0 = blockIdx.x * 64;
  const int n0 = blockIdx.y * 128;
  const int tid = threadIdx.x;
  const int lane = tid & 63;
  const int w = tid >> 6;
  const int l15 = lane & 15;
  const int cg = lane >> 4;

  f32x4 acc[8];
#pragma unroll
  for (int i = 0; i < 8; ++i) acc[i] = (f32x4){0.f, 0.f, 0.f, 0.f};

  const int arow = m0 + w * 16 + l15;
#pragma unroll
  for (int ks = 0; ks < 4; ++ks) {
    bf16x8 ah = ldb8(feh + (size_t)arow * 128 + ks * 32 + cg * 8);
    bf16x8 al = ldb8(fel + (size_t)arow * 128 + ks * 32 + cg * 8);
#pragma unroll
    for (int nt = 0; nt < 8; ++nt) {
      int brow = n0 + nt * 16 + l15;
      bf16x8 bh = ldb8(wih0h + (size_t)brow * 128 + ks * 32 + cg * 8);
      bf16x8 bl = ldb8(wih0l + (size_t)brow * 128 + ks * 32 + cg * 8);
      acc[nt] = __builtin_amdgcn_mfma_f32_16x16x32_bf16(ah, bh, acc[nt], 0, 0, 0);
      acc[nt] = __builtin_amdgcn_mfma_f32_16x16x32_bf16(ah, bl, acc[nt], 0, 0, 0);
      acc[nt] = __builtin_amdgcn_mfma_f32_16x16x32_bf16(al, bh, acc[nt], 0, 0, 0);
    }
  }
#pragma unroll
  for (int nt = 0; nt < 8; ++nt) {
#pragma unroll
    for (int r = 0; r < 4; ++r) {
      xg0[(size_t)(m0 + w * 16 + cg * 4 + r) * 512 + n0 + nt * 16 + l15] = acc[nt][r];
    }
  }
}

// ---------------------------------------------------------------------------
// Kernel 4: LSTM layer 0 with xg prefetch. 32 blocks x 512 thr.
// ---------------------------------------------------------------------------
__global__ __launch_bounds__(512) void k_lstm0(
    const float* __restrict__ xg0, const float* __restrict__ whh0T,
    const int* __restrict__ lengths, float* __restrict__ hs1) {
  __shared__ __align__(16) float h0s[H_];
  __shared__ float gs[512];
  const int b = blockIdx.x;
  const int tid = threadIdx.x;
  float w[128];
#pragma unroll
  for (int k = 0; k < 128; ++k) w[k] = whh0T[k * 512 + tid];
  if (tid < H_) h0s[tid] = 0.f;
  float c = 0.f;
  const int len = lengths[b];
  float xg_cur = xg0[((size_t)(b * T_)) * 512 + tid];
  __syncthreads();
  for (int t = 0; t < len; ++t) {
    float xg_nxt = (t + 1 < len) ? xg0[((size_t)(b * T_ + t + 1)) * 512 + tid] : 0.f;
    float a0 = xg_cur;
    float a1 = 0.f;
#pragma unroll
    for (int k4 = 0; k4 < 32; k4 += 2) {
      float4 h = *(const float4*)(h0s + 4 * k4);
      a0 += h.x * w[4 * k4] + h.y * w[4 * k4 + 1] + h.z * w[4 * k4 + 2] + h.w * w[4 * k4 + 3];
      float4 h2 = *(const float4*)(h0s + 4 * k4 + 4);
      a1 += h2.x * w[4 * k4 + 4] + h2.y * w[4 * k4 + 5] + h2.z * w[4 * k4 + 6] + h2.w * w[4 * k4 + 7];
    }
    gs[tid] = a0 + a1;
    __syncthreads();
    if (tid < H_) {
      float ig = sigmoidf_(gs[tid]);
      float fg = sigmoidf_(gs[H_ + tid]);
      float gg = tanhf(gs[2 * H_ + tid]);
      float og = sigmoidf_(gs[3 * H_ + tid]);
      c = fg * c + ig * gg;
      float hn = og * tanhf(c);
      h0s[tid] = hn;
      hs1[((size_t)(b * T_ + t)) * H_ + tid] = hn;
    }
    __syncthreads();
    xg_cur = xg_nxt;
  }
}

// ---------------------------------------------------------------------------
// Kernel 5: xg1 = hs1 @ wih1^T. 256 blocks x 512 thr. (unchanged)
// ---------------------------------------------------------------------------
__global__ __launch_bounds__(512) void k_xg1(
    const float* __restrict__ hs1, const float* __restrict__ wih1T,
    float* __restrict__ xg1) {
  __shared__ __align__(16) float hsS[8][128];
  const int r0 = blockIdx.x * 8;
  const int tid = threadIdx.x;
  for (int i = tid; i < 8 * 128; i += 512) ((float*)hsS)[i] = hs1[(size_t)r0 * 128 + i];
  __syncthreads();
  float acc[8] = {0.f, 0.f, 0.f, 0.f, 0.f, 0.f, 0.f, 0.f};
#pragma unroll 4
  for (int k4 = 0; k4 < 32; ++k4) {
    float w0 = wih1T[(4 * k4 + 0) * 512 + tid];
    float w1v = wih1T[(4 * k4 + 1) * 512 + tid];
    float w2v = wih1T[(4 * k4 + 2) * 512 + tid];
    float w3v = wih1T[(4 * k4 + 3) * 512 + tid];
#pragma unroll
    for (int i = 0; i < 8; ++i) {
      float4 h = *(const float4*)(&hsS[i][4 * k4]);
      acc[i] += h.x * w0 + h.y * w1v + h.z * w2v + h.w * w3v;
    }
  }
#pragma unroll
  for (int i = 0; i < 8; ++i) xg1[((size_t)(r0 + i)) * 512 + tid] = acc[i];
}

// ---------------------------------------------------------------------------
// Kernel 6: LSTM layer 1 + FC tail, with xg prefetch. 32 blocks x 512 thr.
// ---------------------------------------------------------------------------
__global__ __launch_bounds__(512) void k_lstm1(
    const float* __restrict__ xg1, const float* __restrict__ whh1T,
    const float* __restrict__ fc1, const float* __restrict__ fc2,
    const int* __restrict__ lengths, float* __restrict__ out) {
  __shared__ __align__(16) float h1s[H_];
  __shared__ float gs[512];
  __shared__ float tmp10[10];
  const int b = blockIdx.x;
  const int tid = threadIdx.x;
  float w[128];
#pragma unroll
  for (int k = 0; k < 128; ++k) w[k] = whh1T[k * 512 + tid];
  if (tid < H_) h1s[tid] = 0.f;
  float c = 0.f;
  const int len = lengths[b];
  float xg_cur = xg1[((size_t)(b * T_)) * 512 + tid];
  __syncthreads();
  for (int t = 0; t < len; ++t) {
    float xg_nxt = (t + 1 < len) ? xg1[((size_t)(b * T_ + t + 1)) * 512 + tid] : 0.f;
    float a0 = xg_cur;
    float a1 = 0.f;
#pragma unroll
    for (int k4 = 0; k4 < 32; k4 += 2) {
      float4 h = *(const float4*)(h1s + 4 * k4);
      a0 += h.x * w[4 * k4] + h.y * w[4 * k4 + 1] + h.z * w[4 * k4 + 2] + h.w * w[4 * k4 + 3];
      float4 h2 = *(const float4*)(h1s + 4 * k4 + 4);
      a1 += h2.x * w[4 * k4 + 4] + h2.y * w[4 * k4 + 5] + h2.z * w[4 * k4 + 6] + h2.w * w[4 * k4 + 7];
    }
    gs[tid] = a0 + a1;
    __syncthreads();
    if (tid < H_) {
      float ig = sigmoidf_(gs[tid]);
      float fg = sigmoidf_(gs[H_ + tid]);
      float gg = tanhf(gs[2 * H_ + tid]);
      float og = sigmoidf_(gs[3 * H_ + tid]);
      c = fg * c + ig * gg;
      float hn = og * tanhf(c);
      h1s[tid] = hn;
    }
    __syncthreads();
    xg_cur = xg_nxt;
  }
  if (tid < 10) {
    const float* fr = fc1 + tid * H_;
    float s = 0.f;
#pragma unroll 4
    for (int k = 0; k < H_; ++k) s += h1s[k] * fr[k];
    tmp10[tid] = leakyf(s);
  }
  __syncthreads();
  if (tid < 2) {
    const float* fr = fc2 + tid * 10;
    float s = 0.f;
#pragma unroll
    for (int j = 0; j < 10; ++j) s += tmp10[j] * fr[j];
    out[b * 2 + tid] = leakyf(s);
  }
}

extern "C" void kernel_launch(void* const* d_in, const int* in_sizes, int n_in,
                              void* d_out, int out_size, void* d_ws, size_t ws_size,
                              hipStream_t stream) {
  const float* X = (const float*)d_in[0];
  const int* lengths = (const int*)d_in[1];
  const float* w1 = (const float*)d_in[2];
  const float* w2 = (const float*)d_in[3];
  const float* w3 = (const float*)d_in[4];
  const float* linw = (const float*)d_in[5];
  const float* wih0 = (const float*)d_in[6];
  const float* whh0 = (const float*)d_in[7];
  const float* wih1 = (const float*)d_in[8];
  const float* whh1 = (const float*)d_in[9];
  const float* fc1 = (const float*)d_in[10];
  const float* fc2 = (const float*)d_in[11];

  char* wsb = (char*)d_ws;
  size_t off = 0;
  auto alloc = [&](size_t bytes) {
    char* p = wsb + off;
    off += (bytes + 511) & ~(size_t)511;
    return p;
  };
  unsigned short* s3g = (unsigned short*)alloc(2048 * 1728 * 2);
  unsigned short* feh = (unsigned short*)alloc(2048 * 128 * 2);
  unsigned short* fel = (unsigned short*)alloc(2048 * 128 * 2);
  float* xg0 = (float*)alloc(2048 * 512 * 4);
  unsigned short* w1eh = (unsigned short*)alloc(1024 * 2);
  unsigned short* w1el = (unsigned short*)alloc(1024 * 2);
  unsigned short* w2h = (unsigned short*)alloc(20480 * 2);
  unsigned short* w2l = (unsigned short*)alloc(20480 * 2);
  unsigned short* w3h = (unsigned short*)alloc(5120 * 2);
  unsigned short* w3l = (unsigned short*)alloc(5120 * 2);
  unsigned short* linwh = (unsigned short*)alloc(172800 * 2);
  unsigned short* linwl = (unsigned short*)alloc(172800 * 2);
  unsigned short* wih0h = (unsigned short*)alloc(65536 * 2);
  unsigned short* wih0l = (unsigned short*)alloc(65536 * 2);
  float* whh0T = (float*)alloc(65536 * 4);
  float* wih1T = (float*)alloc(65536 * 4);
  float* whh1T = (float*)alloc(65536 * 4);
  float* hs1 = (float*)alloc(262144 * 4);
  float* xg1 = (float*)alloc(2048 * 512 * 4);

  k_prep<<<1803, 256, 0, stream>>>(w1, w2, w3, linw, wih0, whh0, wih1, whh1,
                                   w1eh, w1el, w2h, w2l, w3h, w3l,
                                   linwh, linwl, wih0h, wih0l,
                                   whh0T, wih1T, whh1T);
  k_conv123<<<2048, 256, 0, stream>>>(X, w1eh, w1el, w2h, w2l, w3h, w3l, s3g);
  k_gemm_fe<<<64, 512, 0, stream>>>(s3g, linwh, linwl, feh, fel);
  k_gemm_xg0<<<dim3(32, 4), 256, 0, stream>>>(feh, fel, wih0h, wih0l, xg0);
  k_lstm0<<<32, 512, 0, stream>>>(xg0, whh0T, lengths, hs1);
  k_xg1<<<256, 512, 0, stream>>>(hs1, wih1T, xg1);
  k_lstm1<<<32, 512, 0, stream>>>(xg1, whh1T, fc1, fc2, lengths, (float*)d_out);
}

// Round 8
// 310.123 us; speedup vs baseline: 1.2229x; 1.2229x over previous
//
#include <hip/hip_runtime.h>
#include <hip/hip_bf16.h>

#define B_ 32
#define T_ 64
#define H_ 128
#define L3OUT 54
#define FLAT_ 1728

typedef __attribute__((ext_vector_type(8))) short bf16x8;
typedef __attribute__((ext_vector_type(4))) float f32x4;

__device__ __forceinline__ float leakyf(float v) { return v > 0.f ? v : 0.01f * v; }
__device__ __forceinline__ float sigmoidf_(float v) { return 1.f / (1.f + expf(-v)); }
__device__ __forceinline__ unsigned int bf16rne(float v) {
  unsigned int b = __float_as_uint(v);
  return (b + 0x7FFFu + ((b >> 16) & 1u)) >> 16;
}
__device__ __forceinline__ bf16x8 ldb8(const unsigned short* p) {
  return *(const bf16x8*)p;
}

// ---------------------------------------------------------------------------
// Kernel 0: weight prep + transposes. (unchanged from round 7)
// ---------------------------------------------------------------------------
__global__ __launch_bounds__(256) void k_prep(
    const float* __restrict__ w1, const float* __restrict__ w2,
    const float* __restrict__ w3, const float* __restrict__ linw,
    const float* __restrict__ wih0, const float* __restrict__ whh0,
    const float* __restrict__ wih1, const float* __restrict__ whh1,
    unsigned short* __restrict__ w1eh, unsigned short* __restrict__ w1el,
    unsigned short* __restrict__ w2h, unsigned short* __restrict__ w2l,
    unsigned short* __restrict__ w3h, unsigned short* __restrict__ w3l,
    unsigned short* __restrict__ linwh, unsigned short* __restrict__ linwl,
    unsigned short* __restrict__ wih0h, unsigned short* __restrict__ wih0l,
    float* __restrict__ whh0T, float* __restrict__ wih1T,
    float* __restrict__ whh1T) {
  const int e = blockIdx.x * 256 + threadIdx.x;
  if (e >= 264960) {
    int e5 = e - 264960;
    int m = e5 >> 16, r = e5 & 65535;
    int k = r >> 9, j = r & 511;
    const float* src = (m == 0) ? whh0 : ((m == 1) ? wih1 : whh1);
    float* dst = (m == 0) ? whh0T : ((m == 1) ? wih1T : whh1T);
    dst[r] = src[j * 128 + k];
    return;
  }
  float v;
  unsigned short* dh;
  unsigned short* dl;
  int di;
  if (e < 20480) {
    int cc = e / 5120, rem = e - cc * 5120;
    int c2 = rem / 160, r = rem - c2 * 160;
    int tap = r >> 5, c1l = r & 31;
    v = w2[c2 * 640 + (cc * 32 + c1l) * 5 + tap];
    dh = w2h; dl = w2l; di = e;
  } else if (e < 25600) {
    int e2 = e - 20480;
    int c3 = e2 / 160, r = e2 - c3 * 160;
    int tap = r >> 5, c2 = r & 31;
    v = w3[c3 * 160 + c2 * 5 + tap];
    dh = w3h; dl = w3l; di = e2;
  } else if (e < 198400) {
    int e3 = e - 25600;
    v = linw[e3];
    dh = linwh; dl = linwl; di = e3;
  } else if (e < 263936) {
    int e4 = e - 198400;
    int g = e4 >> 7, k = e4 & 127;
    v = (k < 100) ? wih0[g * 100 + k] : 0.f;
    dh = wih0h; dl = wih0l; di = e4;
  } else {
    int i = e - 263936;  // 1024: [c1 128][j 8]
    int c1 = i >> 3, j = i & 7;
    v = (j < 5) ? w1[c1 * 5 + j] : 0.f;
    dh = w1eh; dl = w1el; di = i;
  }
  unsigned int hb = bf16rne(v);
  float hf = __uint_as_float(hb << 16);
  unsigned int lb = bf16rne(v - hf);
  dh[di] = (unsigned short)hb;
  dl[di] = (unsigned short)lb;
}

// ---------------------------------------------------------------------------
// Kernel 1: conv1 + conv2 + conv3, all on MFMA. One block per n, 256 thr.
// NEW this round: T2 XOR swizzle on AhU -- word col ^= ((row&3)<<2) on every
// access (write + b128 read use the same involution; XOR is a multiple of 4
// so b64 pairs and b128 quads stay aligned). Removes the 16-lane same-bank
// writes (pos stride 16 rows x 20 words == 0 mod 32).
// ---------------------------------------------------------------------------
__global__ __launch_bounds__(256) void k_conv123(
    const float* __restrict__ X,
    const unsigned short* __restrict__ w1eh, const unsigned short* __restrict__ w1el,
    const unsigned short* __restrict__ w2h, const unsigned short* __restrict__ w2l,
    const unsigned short* __restrict__ w3h, const unsigned short* __restrict__ w3l,
    unsigned short* __restrict__ s3g) {
  __shared__ __align__(16) unsigned short Xwh[4096];  // [512 pos][8 taps]
  __shared__ __align__(16) unsigned short Xwl[4096];
  __shared__ __align__(16) unsigned int AhU[10640];   // [532 rows][20 u32]

  const int n = blockIdx.x;
  const int tid = threadIdx.x;
  const int lane = tid & 63;
  const int w = tid >> 6;
  const int l15 = lane & 15;
  const int cg = lane >> 4;

  // zero AhU pad rows 512..531 (full rows -> swizzle-invariant)
  for (int i = tid; i < 400; i += 256) AhU[10240 + i] = 0u;

  // Phase A: build Xwin hi/lo
  const float* Xn = X + (size_t)n * 1500;
  for (int i = tid; i < 2048; i += 256) {
    int pos = i >> 2, jp = i & 3;
    int s0 = 3 * pos + 2 * jp;
    float v0 = (s0 < 1500) ? Xn[s0] : 0.f;
    float v1 = (s0 + 1 < 1500) ? Xn[s0 + 1] : 0.f;
    unsigned int h0 = bf16rne(v0), h1 = bf16rne(v1);
    float f0 = __uint_as_float(h0 << 16), f1 = __uint_as_float(h1 << 16);
    unsigned int lo0 = bf16rne(v0 - f0), lo1 = bf16rne(v1 - f1);
    ((unsigned int*)Xwh)[i] = h0 | (h1 << 16);
    ((unsigned int*)Xwl)[i] = lo0 | (lo1 << 16);
  }
  __syncthreads();

  const bf16x8 zf = (bf16x8){0, 0, 0, 0, 0, 0, 0, 0};
  f32x4 acc2[3][2];
#pragma unroll
  for (int a = 0; a < 3; ++a)
#pragma unroll
    for (int m = 0; m < 2; ++m) acc2[a][m] = (f32x4){0.f, 0.f, 0.f, 0.f};

  for (int cc = 0; cc < 4; ++cc) {  // 4 chunks of 32 c1
    // ---- conv1 MFMA ----
    bf16x8 afh0 = zf, afh1 = zf, afl0 = zf, afl1 = zf;
    if (cg == 0) {
      afh0 = ldb8(w1eh + ((cc * 2 + 0) * 16 + l15) * 8);
      afh1 = ldb8(w1eh + ((cc * 2 + 1) * 16 + l15) * 8);
      afl0 = ldb8(w1el + ((cc * 2 + 0) * 16 + l15) * 8);
      afl1 = ldb8(w1el + ((cc * 2 + 1) * 16 + l15) * 8);
    }
    f32x4 a1[2][8];
#pragma unroll
    for (int m = 0; m < 2; ++m)
#pragma unroll
      for (int q = 0; q < 8; ++q) a1[m][q] = (f32x4){0.f, 0.f, 0.f, 0.f};
#pragma unroll
    for (int nt8 = 0; nt8 < 8; ++nt8) {
      int nt = w * 8 + nt8;
      bf16x8 bh = zf, bl = zf;
      if (cg == 0) {
        bh = ldb8(Xwh + (nt * 16 + l15) * 8);
        bl = ldb8(Xwl + (nt * 16 + l15) * 8);
      }
      a1[0][nt8] = __builtin_amdgcn_mfma_f32_16x16x32_bf16(afh0, bh, a1[0][nt8], 0, 0, 0);
      a1[0][nt8] = __builtin_amdgcn_mfma_f32_16x16x32_bf16(afl0, bh, a1[0][nt8], 0, 0, 0);
      a1[0][nt8] = __builtin_amdgcn_mfma_f32_16x16x32_bf16(afh0, bl, a1[0][nt8], 0, 0, 0);
      a1[1][nt8] = __builtin_amdgcn_mfma_f32_16x16x32_bf16(afh1, bh, a1[1][nt8], 0, 0, 0);
      a1[1][nt8] = __builtin_amdgcn_mfma_f32_16x16x32_bf16(afl1, bh, a1[1][nt8], 0, 0, 0);
      a1[1][nt8] = __builtin_amdgcn_mfma_f32_16x16x32_bf16(afh1, bl, a1[1][nt8], 0, 0, 0);
    }
    __syncthreads();  // previous chunk's conv2 reads of AhU are done
    // ---- epilogue: leaky + bf16 pack -> AhU (swizzled, conflict-free) ----
#pragma unroll
    for (int nt8 = 0; nt8 < 8; ++nt8) {
      int pos = (w * 8 + nt8) * 16 + l15;
      const int xr = (pos & 3) << 2;
#pragma unroll
      for (int mt2 = 0; mt2 < 2; ++mt2) {
        float e0 = leakyf(a1[mt2][nt8][0]);
        float e1 = leakyf(a1[mt2][nt8][1]);
        float e2 = leakyf(a1[mt2][nt8][2]);
        float e3 = leakyf(a1[mt2][nt8][3]);
        uint2 pk;
        pk.x = bf16rne(e0) | (bf16rne(e1) << 16);
        pk.y = bf16rne(e2) | (bf16rne(e3) << 16);
        *(uint2*)(&AhU[pos * 20 + ((mt2 * 8 + cg * 2) ^ xr)]) = pk;
      }
    }
    __syncthreads();
    // ---- conv2 MFMA over this chunk ----
    const unsigned short* w2hB = w2h + cc * 5120;
    const unsigned short* w2lB = w2l + cc * 5120;
#pragma unroll
    for (int tap = 0; tap < 5; ++tap) {
      const int wc = tap * 32 + cg * 8;
      bf16x8 ah0 = ldb8(w2hB + l15 * 160 + wc);
      bf16x8 ah1 = ldb8(w2hB + (l15 + 16) * 160 + wc);
      bf16x8 al0 = ldb8(w2lB + l15 * 160 + wc);
      bf16x8 al1 = ldb8(w2lB + (l15 + 16) * 160 + wc);
#pragma unroll
      for (int nti = 0; nti < 3; ++nti) {
        int nt = w + 4 * nti;
        if (nt < 11) {
          int row = 3 * (nt * 16 + l15) + tap;
          bf16x8 bfr = ldb8((const unsigned short*)AhU + row * 40 +
                            ((cg * 8) ^ ((row & 3) << 3)));
          acc2[nti][0] = __builtin_amdgcn_mfma_f32_16x16x32_bf16(ah0, bfr, acc2[nti][0], 0, 0, 0);
          acc2[nti][0] = __builtin_amdgcn_mfma_f32_16x16x32_bf16(al0, bfr, acc2[nti][0], 0, 0, 0);
          acc2[nti][1] = __builtin_amdgcn_mfma_f32_16x16x32_bf16(ah1, bfr, acc2[nti][1], 0, 0, 0);
          acc2[nti][1] = __builtin_amdgcn_mfma_f32_16x16x32_bf16(al1, bfr, acc2[nti][1], 0, 0, 0);
        }
      }
    }
  }
  __syncthreads();  // all conv2 MFMA reads of AhU done
  // A3 (aliases AhU): rows = l2, swizzled writes; zero pad rows fully
  for (int i = tid; i < 400; i += 256) AhU[176 * 20 + i] = 0u;
#pragma unroll
  for (int nti = 0; nti < 3; ++nti) {
    int nt = w + 4 * nti;
    if (nt < 11) {
      int l2 = nt * 16 + l15;
      const int xr = (l2 & 3) << 2;
#pragma unroll
      for (int mt = 0; mt < 2; ++mt) {
#pragma unroll
        for (int j = 0; j < 2; ++j) {
          float e0 = leakyf(acc2[nti][mt][2 * j]);
          float e1 = leakyf(acc2[nti][mt][2 * j + 1]);
          AhU[l2 * 20 + ((mt * 8 + cg * 2 + j) ^ xr)] = bf16rne(e0) | (bf16rne(e1) << 16);
        }
      }
    }
  }
  __syncthreads();
  // conv3 MFMA
  f32x4 a3[2];
  a3[0] = (f32x4){0.f, 0.f, 0.f, 0.f};
  a3[1] = (f32x4){0.f, 0.f, 0.f, 0.f};
#pragma unroll
  for (int tap = 0; tap < 5; ++tap) {
    const int wc = tap * 32 + cg * 8;
    bf16x8 wh0 = ldb8(w3h + l15 * 160 + wc);
    bf16x8 wh1 = ldb8(w3h + (l15 + 16) * 160 + wc);
    bf16x8 wl0 = ldb8(w3l + l15 * 160 + wc);
    bf16x8 wl1 = ldb8(w3l + (l15 + 16) * 160 + wc);
    int row = 3 * (w * 16 + l15) + tap;
    bf16x8 bfr = ldb8((const unsigned short*)AhU + row * 40 +
                      ((cg * 8) ^ ((row & 3) << 3)));
    a3[0] = __builtin_amdgcn_mfma_f32_16x16x32_bf16(wh0, bfr, a3[0], 0, 0, 0);
    a3[0] = __builtin_amdgcn_mfma_f32_16x16x32_bf16(wl0, bfr, a3[0], 0, 0, 0);
    a3[1] = __builtin_amdgcn_mfma_f32_16x16x32_bf16(wh1, bfr, a3[1], 0, 0, 0);
    a3[1] = __builtin_amdgcn_mfma_f32_16x16x32_bf16(wl1, bfr, a3[1], 0, 0, 0);
  }
  int l3 = w * 16 + l15;
  if (l3 < L3OUT) {
#pragma unroll
    for (int mt = 0; mt < 2; ++mt) {
#pragma unroll
      for (int r = 0; r < 4; ++r) {
        int c3 = mt * 16 + cg * 4 + r;
        s3g[(size_t)n * FLAT_ + c3 * L3OUT + l3] = (unsigned short)bf16rne(leakyf(a3[mt][r]));
      }
    }
  }
}

// ---------------------------------------------------------------------------
// Kernel 2: GEMM-1 fe = s3g @ linw-hl^T -- global-direct, no LDS, no barrier.
// 128 blocks (M-tile 16) x 448 thr (7 waves = 7 n-tiles). 54 K-steps,
// 3 global b128 + 2 MFMA each, deep unroll for vmcnt pipelining.
// linw rows >99 clamped (finite garbage x zero wih0 pad weights).
// ---------------------------------------------------------------------------
__global__ __launch_bounds__(448) void k_gemm_fe(
    const unsigned short* __restrict__ s3g,
    const unsigned short* __restrict__ linwh, const unsigned short* __restrict__ linwl,
    unsigned short* __restrict__ feh, unsigned short* __restrict__ fel) {
  const int m0 = blockIdx.x * 16;
  const int tid = threadIdx.x;
  const int lane = tid & 63;
  const int w = tid >> 6;  // 0..6
  const int l15 = lane & 15;
  const int cg = lane >> 4;

  int brow = w * 16 + l15;
  if (brow > 99) brow = 99;
  const unsigned short* ap = s3g + (size_t)(m0 + l15) * FLAT_ + cg * 8;
  const unsigned short* bhp = linwh + (size_t)brow * FLAT_ + cg * 8;
  const unsigned short* blp = linwl + (size_t)brow * FLAT_ + cg * 8;

  f32x4 acc = (f32x4){0.f, 0.f, 0.f, 0.f};
#pragma unroll 6
  for (int ks = 0; ks < 54; ++ks) {
    bf16x8 af = ldb8(ap + ks * 32);
    bf16x8 bh = ldb8(bhp + ks * 32);
    bf16x8 bl = ldb8(blp + ks * 32);
    acc = __builtin_amdgcn_mfma_f32_16x16x32_bf16(af, bh, acc, 0, 0, 0);
    acc = __builtin_amdgcn_mfma_f32_16x16x32_bf16(af, bl, acc, 0, 0, 0);
  }
  const int jcol = w * 16 + l15;
  const int sample = m0 + cg * 4;
#pragma unroll
  for (int r = 0; r < 4; ++r) {
    float v = acc[r];
    unsigned int hb = bf16rne(v);
    float hf = __uint_as_float(hb << 16);
    unsigned int lb = bf16rne(v - hf);
    feh[(size_t)(sample + r) * 128 + jcol] = (unsigned short)hb;
    fel[(size_t)(sample + r) * 128 + jcol] = (unsigned short)lb;
  }
}

// ---------------------------------------------------------------------------
// Kernel 3: GEMM-2  xg0 = fe-hl @ wih0-hl^T. (unchanged)
// ---------------------------------------------------------------------------
__global__ __launch_bounds__(256) void k_gemm_xg0(
    const unsigned short* __restrict__ feh, const unsigned short* __restrict__ fel,
    const unsigned short* __restrict__ wih0h, const unsigned short* __restrict__ wih0l,
    float* __restrict__ xg0) {
  const int m0 = blockIdx.x * 64;
  const int n0 = blockIdx.y * 128;
  const int tid = threadIdx.x;
  const int lane = tid & 63;
  const int w = tid >> 6;
  const int l15 = lane & 15;
  const int cg = lane >> 4;

  f32x4 acc[8];
#pragma unroll
  for (int i = 0; i < 8; ++i) acc[i] = (f32x4){0.f, 0.f, 0.f, 0.f};

  const int arow = m0 + w * 16 + l15;
#pragma unroll
  for (int ks = 0; ks < 4; ++ks) {
    bf16x8 ah = ldb8(feh + (size_t)arow * 128 + ks * 32 + cg * 8);
    bf16x8 al = ldb8(fel + (size_t)arow * 128 + ks * 32 + cg * 8);
#pragma unroll
    for (int nt = 0; nt < 8; ++nt) {
      int brow = n0 + nt * 16 + l15;
      bf16x8 bh = ldb8(wih0h + (size_t)brow * 128 + ks * 32 + cg * 8);
      bf16x8 bl = ldb8(wih0l + (size_t)brow * 128 + ks * 32 + cg * 8);
      acc[nt] = __builtin_amdgcn_mfma_f32_16x16x32_bf16(ah, bh, acc[nt], 0, 0, 0);
      acc[nt] = __builtin_amdgcn_mfma_f32_16x16x32_bf16(ah, bl, acc[nt], 0, 0, 0);
      acc[nt] = __builtin_amdgcn_mfma_f32_16x16x32_bf16(al, bh, acc[nt], 0, 0, 0);
    }
  }
#pragma unroll
  for (int nt = 0; nt < 8; ++nt) {
#pragma unroll
    for (int r = 0; r < 4; ++r) {
      xg0[(size_t)(m0 + w * 16 + cg * 4 + r) * 512 + n0 + nt * 16 + l15] = acc[nt][r];
    }
  }
}

// ---------------------------------------------------------------------------
// Kernel 4: LSTM layer 0. NEW: per-gate activation applied in the dot phase
// (wave-uniform branch); tid<128 tail shrinks to c/h update + one tanh.
// ---------------------------------------------------------------------------
__global__ __launch_bounds__(512) void k_lstm0(
    const float* __restrict__ xg0, const float* __restrict__ whh0T,
    const int* __restrict__ lengths, float* __restrict__ hs1) {
  __shared__ __align__(16) float h0s[H_];
  __shared__ float gs[512];
  const int b = blockIdx.x;
  const int tid = threadIdx.x;
  float w[128];
#pragma unroll
  for (int k = 0; k < 128; ++k) w[k] = whh0T[k * 512 + tid];
  if (tid < H_) h0s[tid] = 0.f;
  float c = 0.f;
  const int len = lengths[b];
  const bool isg = (tid >= 256 && tid < 384);
  float xg_cur = xg0[((size_t)(b * T_)) * 512 + tid];
  __syncthreads();
  for (int t = 0; t < len; ++t) {
    float xg_nxt = (t + 1 < len) ? xg0[((size_t)(b * T_ + t + 1)) * 512 + tid] : 0.f;
    float a0 = xg_cur;
    float a1 = 0.f;
#pragma unroll
    for (int k4 = 0; k4 < 32; k4 += 2) {
      float4 h = *(const float4*)(h0s + 4 * k4);
      a0 += h.x * w[4 * k4] + h.y * w[4 * k4 + 1] + h.z * w[4 * k4 + 2] + h.w * w[4 * k4 + 3];
      float4 h2 = *(const float4*)(h0s + 4 * k4 + 4);
      a1 += h2.x * w[4 * k4 + 4] + h2.y * w[4 * k4 + 5] + h2.z * w[4 * k4 + 6] + h2.w * w[4 * k4 + 7];
    }
    float av = a0 + a1;
    gs[tid] = isg ? tanhf(av) : sigmoidf_(av);
    __syncthreads();
    if (tid < H_) {
      float ig = gs[tid];
      float fg = gs[H_ + tid];
      float gg = gs[2 * H_ + tid];
      float og = gs[3 * H_ + tid];
      c = fg * c + ig * gg;
      float hn = og * tanhf(c);
      h0s[tid] = hn;
      hs1[((size_t)(b * T_ + t)) * H_ + tid] = hn;
    }
    __syncthreads();
    xg_cur = xg_nxt;
  }
}

// ---------------------------------------------------------------------------
// Kernel 5: xg1 = hs1 @ wih1^T. (unchanged)
// ---------------------------------------------------------------------------
__global__ __launch_bounds__(512) void k_xg1(
    const float* __restrict__ hs1, const float* __restrict__ wih1T,
    float* __restrict__ xg1) {
  __shared__ __align__(16) float hsS[8][128];
  const int r0 = blockIdx.x * 8;
  const int tid = threadIdx.x;
  for (int i = tid; i < 8 * 128; i += 512) ((float*)hsS)[i] = hs1[(size_t)r0 * 128 + i];
  __syncthreads();
  float acc[8] = {0.f, 0.f, 0.f, 0.f, 0.f, 0.f, 0.f, 0.f};
#pragma unroll 4
  for (int k4 = 0; k4 < 32; ++k4) {
    float w0 = wih1T[(4 * k4 + 0) * 512 + tid];
    float w1v = wih1T[(4 * k4 + 1) * 512 + tid];
    float w2v = wih1T[(4 * k4 + 2) * 512 + tid];
    float w3v = wih1T[(4 * k4 + 3) * 512 + tid];
#pragma unroll
    for (int i = 0; i < 8; ++i) {
      float4 h = *(const float4*)(&hsS[i][4 * k4]);
      acc[i] += h.x * w0 + h.y * w1v + h.z * w2v + h.w * w3v;
    }
  }
#pragma unroll
  for (int i = 0; i < 8; ++i) xg1[((size_t)(r0 + i)) * 512 + tid] = acc[i];
}

// ---------------------------------------------------------------------------
// Kernel 6: LSTM layer 1 + FC tail. Same activation-in-dot refactor.
// ---------------------------------------------------------------------------
__global__ __launch_bounds__(512) void k_lstm1(
    const float* __restrict__ xg1, const float* __restrict__ whh1T,
    const float* __restrict__ fc1, const float* __restrict__ fc2,
    const int* __restrict__ lengths, float* __restrict__ out) {
  __shared__ __align__(16) float h1s[H_];
  __shared__ float gs[512];
  __shared__ float tmp10[10];
  const int b = blockIdx.x;
  const int tid = threadIdx.x;
  float w[128];
#pragma unroll
  for (int k = 0; k < 128; ++k) w[k] = whh1T[k * 512 + tid];
  if (tid < H_) h1s[tid] = 0.f;
  float c = 0.f;
  const int len = lengths[b];
  const bool isg = (tid >= 256 && tid < 384);
  float xg_cur = xg1[((size_t)(b * T_)) * 512 + tid];
  __syncthreads();
  for (int t = 0; t < len; ++t) {
    float xg_nxt = (t + 1 < len) ? xg1[((size_t)(b * T_ + t + 1)) * 512 + tid] : 0.f;
    float a0 = xg_cur;
    float a1 = 0.f;
#pragma unroll
    for (int k4 = 0; k4 < 32; k4 += 2) {
      float4 h = *(const float4*)(h1s + 4 * k4);
      a0 += h.x * w[4 * k4] + h.y * w[4 * k4 + 1] + h.z * w[4 * k4 + 2] + h.w * w[4 * k4 + 3];
      float4 h2 = *(const float4*)(h1s + 4 * k4 + 4);
      a1 += h2.x * w[4 * k4 + 4] + h2.y * w[4 * k4 + 5] + h2.z * w[4 * k4 + 6] + h2.w * w[4 * k4 + 7];
    }
    float av = a0 + a1;
    gs[tid] = isg ? tanhf(av) : sigmoidf_(av);
    __syncthreads();
    if (tid < H_) {
      float ig = gs[tid];
      float fg = gs[H_ + tid];
      float gg = gs[2 * H_ + tid];
      float og = gs[3 * H_ + tid];
      c = fg * c + ig * gg;
      float hn = og * tanhf(c);
      h1s[tid] = hn;
    }
    __syncthreads();
    xg_cur = xg_nxt;
  }
  if (tid < 10) {
    const float* fr = fc1 + tid * H_;
    float s = 0.f;
#pragma unroll 4
    for (int k = 0; k < H_; ++k) s += h1s[k] * fr[k];
    tmp10[tid] = leakyf(s);
  }
  __syncthreads();
  if (tid < 2) {
    const float* fr = fc2 + tid * 10;
    float s = 0.f;
#pragma unroll
    for (int j = 0; j < 10; ++j) s += tmp10[j] * fr[j];
    out[b * 2 + tid] = leakyf(s);
  }
}

extern "C" void kernel_launch(void* const* d_in, const int* in_sizes, int n_in,
                              void* d_out, int out_size, void* d_ws, size_t ws_size,
                              hipStream_t stream) {
  const float* X = (const float*)d_in[0];
  const int* lengths = (const int*)d_in[1];
  const float* w1 = (const float*)d_in[2];
  const float* w2 = (const float*)d_in[3];
  const float* w3 = (const float*)d_in[4];
  const float* linw = (const float*)d_in[5];
  const float* wih0 = (const float*)d_in[6];
  const float* whh0 = (const float*)d_in[7];
  const float* wih1 = (const float*)d_in[8];
  const float* whh1 = (const float*)d_in[9];
  const float* fc1 = (const float*)d_in[10];
  const float* fc2 = (const float*)d_in[11];

  char* wsb = (char*)d_ws;
  size_t off = 0;
  auto alloc = [&](size_t bytes) {
    char* p = wsb + off;
    off += (bytes + 511) & ~(size_t)511;
    return p;
  };
  unsigned short* s3g = (unsigned short*)alloc(2048 * 1728 * 2);
  unsigned short* feh = (unsigned short*)alloc(2048 * 128 * 2);
  unsigned short* fel = (unsigned short*)alloc(2048 * 128 * 2);
  float* xg0 = (float*)alloc(2048 * 512 * 4);
  unsigned short* w1eh = (unsigned short*)alloc(1024 * 2);
  unsigned short* w1el = (unsigned short*)alloc(1024 * 2);
  unsigned short* w2h = (unsigned short*)alloc(20480 * 2);
  unsigned short* w2l = (unsigned short*)alloc(20480 * 2);
  unsigned short* w3h = (unsigned short*)alloc(5120 * 2);
  unsigned short* w3l = (unsigned short*)alloc(5120 * 2);
  unsigned short* linwh = (unsigned short*)alloc(172800 * 2);
  unsigned short* linwl = (unsigned short*)alloc(172800 * 2);
  unsigned short* wih0h = (unsigned short*)alloc(65536 * 2);
  unsigned short* wih0l = (unsigned short*)alloc(65536 * 2);
  float* whh0T = (float*)alloc(65536 * 4);
  float* wih1T = (float*)alloc(65536 * 4);
  float* whh1T = (float*)alloc(65536 * 4);
  float* hs1 = (float*)alloc(262144 * 4);
  float* xg1 = (float*)alloc(2048 * 512 * 4);

  k_prep<<<1803, 256, 0, stream>>>(w1, w2, w3, linw, wih0, whh0, wih1, whh1,
                                   w1eh, w1el, w2h, w2l, w3h, w3l,
                                   linwh, linwl, wih0h, wih0l,
                                   whh0T, wih1T, whh1T);
  k_conv123<<<2048, 256, 0, stream>>>(X, w1eh, w1el, w2h, w2l, w3h, w3l, s3g);
  k_gemm_fe<<<128, 448, 0, stream>>>(s3g, linwh, linwl, feh, fel);
  k_gemm_xg0<<<dim3(32, 4), 256, 0, stream>>>(feh, fel, wih0h, wih0l, xg0);
  k_lstm0<<<32, 512, 0, stream>>>(xg0, whh0T, lengths, hs1);
  k_xg1<<<256, 512, 0, stream>>>(hs1, wih1T, xg1);
  k_lstm1<<<32, 512, 0, stream>>>(xg1, whh1T, fc1, fc2, lengths, (float*)d_out);
}

// Round 9
// 296.814 us; speedup vs baseline: 1.2777x; 1.0448x over previous
//
#include <hip/hip_runtime.h>
#include <hip/hip_bf16.h>

#define B_ 32
#define T_ 64
#define H_ 128
#define L3OUT 54
#define FLAT_ 1728

typedef __attribute__((ext_vector_type(8))) short bf16x8;
typedef __attribute__((ext_vector_type(4))) float f32x4;

__device__ __forceinline__ float leakyf(float v) { return v > 0.f ? v : 0.01f * v; }
__device__ __forceinline__ float sigmoidf_(float v) { return 1.f / (1.f + expf(-v)); }
__device__ __forceinline__ unsigned int bf16rne(float v) {
  unsigned int b = __float_as_uint(v);
  return (b + 0x7FFFu + ((b >> 16) & 1u)) >> 16;
}
__device__ __forceinline__ bf16x8 ldb8(const unsigned short* p) {
  return *(const bf16x8*)p;
}

// ---------------------------------------------------------------------------
// Kernel 0: weight prep + transposes. (unchanged)
// ---------------------------------------------------------------------------
__global__ __launch_bounds__(256) void k_prep(
    const float* __restrict__ w1, const float* __restrict__ w2,
    const float* __restrict__ w3, const float* __restrict__ linw,
    const float* __restrict__ wih0, const float* __restrict__ whh0,
    const float* __restrict__ wih1, const float* __restrict__ whh1,
    unsigned short* __restrict__ w1eh, unsigned short* __restrict__ w1el,
    unsigned short* __restrict__ w2h, unsigned short* __restrict__ w2l,
    unsigned short* __restrict__ w3h, unsigned short* __restrict__ w3l,
    unsigned short* __restrict__ linwh, unsigned short* __restrict__ linwl,
    unsigned short* __restrict__ wih0h, unsigned short* __restrict__ wih0l,
    float* __restrict__ whh0T, float* __restrict__ wih1T,
    float* __restrict__ whh1T) {
  const int e = blockIdx.x * 256 + threadIdx.x;
  if (e >= 264960) {
    int e5 = e - 264960;
    int m = e5 >> 16, r = e5 & 65535;
    int k = r >> 9, j = r & 511;
    const float* src = (m == 0) ? whh0 : ((m == 1) ? wih1 : whh1);
    float* dst = (m == 0) ? whh0T : ((m == 1) ? wih1T : whh1T);
    dst[r] = src[j * 128 + k];
    return;
  }
  float v;
  unsigned short* dh;
  unsigned short* dl;
  int di;
  if (e < 20480) {
    int cc = e / 5120, rem = e - cc * 5120;
    int c2 = rem / 160, r = rem - c2 * 160;
    int tap = r >> 5, c1l = r & 31;
    v = w2[c2 * 640 + (cc * 32 + c1l) * 5 + tap];
    dh = w2h; dl = w2l; di = e;
  } else if (e < 25600) {
    int e2 = e - 20480;
    int c3 = e2 / 160, r = e2 - c3 * 160;
    int tap = r >> 5, c2 = r & 31;
    v = w3[c3 * 160 + c2 * 5 + tap];
    dh = w3h; dl = w3l; di = e2;
  } else if (e < 198400) {
    int e3 = e - 25600;
    v = linw[e3];
    dh = linwh; dl = linwl; di = e3;
  } else if (e < 263936) {
    int e4 = e - 198400;
    int g = e4 >> 7, k = e4 & 127;
    v = (k < 100) ? wih0[g * 100 + k] : 0.f;
    dh = wih0h; dl = wih0l; di = e4;
  } else {
    int i = e - 263936;
    int c1 = i >> 3, j = i & 7;
    v = (j < 5) ? w1[c1 * 5 + j] : 0.f;
    dh = w1eh; dl = w1el; di = i;
  }
  unsigned int hb = bf16rne(v);
  float hf = __uint_as_float(hb << 16);
  unsigned int lb = bf16rne(v - hf);
  dh[di] = (unsigned short)hb;
  dl[di] = (unsigned short)lb;
}

// ---------------------------------------------------------------------------
// Kernel 1: conv1 (fp32) + conv2 (MFMA) + conv3 (MFMA). One block per n,
// NOW 512 threads (8 waves): phases halve, 48.6 KB LDS -> 3 blocks/CU.
// Reverted to round-6 AhU layout (rows of 20 u32, NO swizzle -- round-8
// swizzle measured as a conflict regression).
// Wave w owns conv2 n-tiles {w} and {8+w | w<3}; conv3 on waves 0..3.
// ---------------------------------------------------------------------------
__global__ __launch_bounds__(512) void k_conv123(
    const float* __restrict__ X, const float* __restrict__ w1,
    const unsigned short* __restrict__ w2h, const unsigned short* __restrict__ w2l,
    const unsigned short* __restrict__ w3h, const unsigned short* __restrict__ w3l,
    unsigned short* __restrict__ s3g) {
  __shared__ __align__(16) float Xs[1504];
  __shared__ __align__(16) unsigned int AhU[10640];  // [532 rows][20 u32]

  const int n = blockIdx.x;
  const int tid = threadIdx.x;
  const int lane = tid & 63;
  const int w = tid >> 6;        // 0..7
  const int l15 = lane & 15;
  const int cg = lane >> 4;
  const int pr = tid & 15;       // c1-pair in chunk
  const int po = tid >> 4;       // 0..31

  const float* Xn = X + (size_t)n * 1500;
  for (int i = tid; i < 1500; i += 512) Xs[i] = Xn[i];
  if (tid < 4) Xs[1500 + tid] = 0.f;
  for (int i = tid; i < 640; i += 512) AhU[10000 + i] = 0u;  // rows 500..531

  f32x4 acc2[2][2];
#pragma unroll
  for (int a = 0; a < 2; ++a)
#pragma unroll
    for (int m = 0; m < 2; ++m) acc2[a][m] = (f32x4){0.f, 0.f, 0.f, 0.f};

  for (int cc = 0; cc < 4; ++cc) {  // 4 chunks of 32 c1
    __syncthreads();                // previous chunk's conv2 reads done
    // ---- conv1 fp32: c1 pair (2pr,2pr+1), positions po+32i ----
    const float* wA = w1 + (cc * 32 + 2 * pr) * 5;
    float a0 = wA[0], a1 = wA[1], a2 = wA[2], a3 = wA[3], a4 = wA[4];
    float b0 = wA[5], b1 = wA[6], b2 = wA[7], b3 = wA[8], b4 = wA[9];
#pragma unroll 2
    for (int i = 0; i < 16; ++i) {
      int pos = po + 32 * i;
      if (pos < 500) {
        const float* xp = Xs + 3 * pos;
        float x0 = xp[0], x1 = xp[1], x2 = xp[2], x3 = xp[3], x4 = xp[4];
        float vA = fmaf(x4, a4, fmaf(x3, a3, fmaf(x2, a2, fmaf(x1, a1, x0 * a0))));
        float vB = fmaf(x4, b4, fmaf(x3, b3, fmaf(x2, b2, fmaf(x1, b1, x0 * b0))));
        vA = leakyf(vA);
        vB = leakyf(vB);
        AhU[pos * 20 + pr] = bf16rne(vA) | (bf16rne(vB) << 16);
      }
    }
    __syncthreads();
    // ---- conv2 MFMA over this chunk ----
    const unsigned short* w2hB = w2h + cc * 5120;
    const unsigned short* w2lB = w2l + cc * 5120;
#pragma unroll
    for (int tap = 0; tap < 5; ++tap) {
      const int wc = tap * 32 + cg * 8;
      bf16x8 ah0 = ldb8(w2hB + l15 * 160 + wc);
      bf16x8 ah1 = ldb8(w2hB + (l15 + 16) * 160 + wc);
      bf16x8 al0 = ldb8(w2lB + l15 * 160 + wc);
      bf16x8 al1 = ldb8(w2lB + (l15 + 16) * 160 + wc);
      {  // n-tile w
        bf16x8 bfr = ldb8((const unsigned short*)AhU + (3 * (w * 16 + l15) + tap) * 40 + cg * 8);
        acc2[0][0] = __builtin_amdgcn_mfma_f32_16x16x32_bf16(ah0, bfr, acc2[0][0], 0, 0, 0);
        acc2[0][0] = __builtin_amdgcn_mfma_f32_16x16x32_bf16(al0, bfr, acc2[0][0], 0, 0, 0);
        acc2[0][1] = __builtin_amdgcn_mfma_f32_16x16x32_bf16(ah1, bfr, acc2[0][1], 0, 0, 0);
        acc2[0][1] = __builtin_amdgcn_mfma_f32_16x16x32_bf16(al1, bfr, acc2[0][1], 0, 0, 0);
      }
      if (w < 3) {  // n-tile 8+w
        int nt = 8 + w;
        bf16x8 bfr = ldb8((const unsigned short*)AhU + (3 * (nt * 16 + l15) + tap) * 40 + cg * 8);
        acc2[1][0] = __builtin_amdgcn_mfma_f32_16x16x32_bf16(ah0, bfr, acc2[1][0], 0, 0, 0);
        acc2[1][0] = __builtin_amdgcn_mfma_f32_16x16x32_bf16(al0, bfr, acc2[1][0], 0, 0, 0);
        acc2[1][1] = __builtin_amdgcn_mfma_f32_16x16x32_bf16(ah1, bfr, acc2[1][1], 0, 0, 0);
        acc2[1][1] = __builtin_amdgcn_mfma_f32_16x16x32_bf16(al1, bfr, acc2[1][1], 0, 0, 0);
      }
    }
  }
  __syncthreads();  // all conv2 reads of AhU done
  // A3 (aliases AhU): rows = l2; zero pad rows 176..195
  for (int i = tid; i < 400; i += 512) AhU[176 * 20 + i] = 0u;
#pragma unroll
  for (int nti = 0; nti < 2; ++nti) {
    int nt = (nti == 0) ? w : (8 + w);
    if (nti == 0 || w < 3) {
      int l2 = nt * 16 + l15;
#pragma unroll
      for (int mt = 0; mt < 2; ++mt) {
#pragma unroll
        for (int j = 0; j < 2; ++j) {
          float e0 = leakyf(acc2[nti][mt][2 * j]);
          float e1 = leakyf(acc2[nti][mt][2 * j + 1]);
          AhU[l2 * 20 + mt * 8 + cg * 2 + j] = bf16rne(e0) | (bf16rne(e1) << 16);
        }
      }
    }
  }
  __syncthreads();
  // conv3 MFMA: waves 0..3 (l3 tile = w)
  if (w < 4) {
    f32x4 a3[2];
    a3[0] = (f32x4){0.f, 0.f, 0.f, 0.f};
    a3[1] = (f32x4){0.f, 0.f, 0.f, 0.f};
#pragma unroll
    for (int tap = 0; tap < 5; ++tap) {
      const int wc = tap * 32 + cg * 8;
      bf16x8 wh0 = ldb8(w3h + l15 * 160 + wc);
      bf16x8 wh1 = ldb8(w3h + (l15 + 16) * 160 + wc);
      bf16x8 wl0 = ldb8(w3l + l15 * 160 + wc);
      bf16x8 wl1 = ldb8(w3l + (l15 + 16) * 160 + wc);
      bf16x8 bfr = ldb8((const unsigned short*)AhU + (3 * (w * 16 + l15) + tap) * 40 + cg * 8);
      a3[0] = __builtin_amdgcn_mfma_f32_16x16x32_bf16(wh0, bfr, a3[0], 0, 0, 0);
      a3[0] = __builtin_amdgcn_mfma_f32_16x16x32_bf16(wl0, bfr, a3[0], 0, 0, 0);
      a3[1] = __builtin_amdgcn_mfma_f32_16x16x32_bf16(wh1, bfr, a3[1], 0, 0, 0);
      a3[1] = __builtin_amdgcn_mfma_f32_16x16x32_bf16(wl1, bfr, a3[1], 0, 0, 0);
    }
    int l3 = w * 16 + l15;
    if (l3 < L3OUT) {
#pragma unroll
      for (int mt = 0; mt < 2; ++mt) {
#pragma unroll
        for (int r = 0; r < 4; ++r) {
          int c3 = mt * 16 + cg * 4 + r;
          s3g[(size_t)n * FLAT_ + c3 * L3OUT + l3] = (unsigned short)bf16rne(leakyf(a3[mt][r]));
        }
      }
    }
  }
}

// ---------------------------------------------------------------------------
// Kernel 2: GEMM-1 fe = s3g @ linw-hl^T -- global-direct. (unchanged)
// ---------------------------------------------------------------------------
__global__ __launch_bounds__(448) void k_gemm_fe(
    const unsigned short* __restrict__ s3g,
    const unsigned short* __restrict__ linwh, const unsigned short* __restrict__ linwl,
    unsigned short* __restrict__ feh, unsigned short* __restrict__ fel) {
  const int m0 = blockIdx.x * 16;
  const int tid = threadIdx.x;
  const int lane = tid & 63;
  const int w = tid >> 6;
  const int l15 = lane & 15;
  const int cg = lane >> 4;

  int brow = w * 16 + l15;
  if (brow > 99) brow = 99;
  const unsigned short* ap = s3g + (size_t)(m0 + l15) * FLAT_ + cg * 8;
  const unsigned short* bhp = linwh + (size_t)brow * FLAT_ + cg * 8;
  const unsigned short* blp = linwl + (size_t)brow * FLAT_ + cg * 8;

  f32x4 acc = (f32x4){0.f, 0.f, 0.f, 0.f};
#pragma unroll 6
  for (int ks = 0; ks < 54; ++ks) {
    bf16x8 af = ldb8(ap + ks * 32);
    bf16x8 bh = ldb8(bhp + ks * 32);
    bf16x8 bl = ldb8(blp + ks * 32);
    acc = __builtin_amdgcn_mfma_f32_16x16x32_bf16(af, bh, acc, 0, 0, 0);
    acc = __builtin_amdgcn_mfma_f32_16x16x32_bf16(af, bl, acc, 0, 0, 0);
  }
  const int jcol = w * 16 + l15;
  const int sample = m0 + cg * 4;
#pragma unroll
  for (int r = 0; r < 4; ++r) {
    float v = acc[r];
    unsigned int hb = bf16rne(v);
    float hf = __uint_as_float(hb << 16);
    unsigned int lb = bf16rne(v - hf);
    feh[(size_t)(sample + r) * 128 + jcol] = (unsigned short)hb;
    fel[(size_t)(sample + r) * 128 + jcol] = (unsigned short)lb;
  }
}

// ---------------------------------------------------------------------------
// Kernel 3: GEMM-2  xg0 = fe-hl @ wih0-hl^T. (unchanged)
// ---------------------------------------------------------------------------
__global__ __launch_bounds__(256) void k_gemm_xg0(
    const unsigned short* __restrict__ feh, const unsigned short* __restrict__ fel,
    const unsigned short* __restrict__ wih0h, const unsigned short* __restrict__ wih0l,
    float* __restrict__ xg0) {
  const int m0 = blockIdx.x * 64;
  const int n0 = blockIdx.y * 128;
  const int tid = threadIdx.x;
  const int lane = tid & 63;
  const int w = tid >> 6;
  const int l15 = lane & 15;
  const int cg = lane >> 4;

  f32x4 acc[8];
#pragma unroll
  for (int i = 0; i < 8; ++i) acc[i] = (f32x4){0.f, 0.f, 0.f, 0.f};

  const int arow = m0 + w * 16 + l15;
#pragma unroll
  for (int ks = 0; ks < 4; ++ks) {
    bf16x8 ah = ldb8(feh + (size_t)arow * 128 + ks * 32 + cg * 8);
    bf16x8 al = ldb8(fel + (size_t)arow * 128 + ks * 32 + cg * 8);
#pragma unroll
    for (int nt = 0; nt < 8; ++nt) {
      int brow = n0 + nt * 16 + l15;
      bf16x8 bh = ldb8(wih0h + (size_t)brow * 128 + ks * 32 + cg * 8);
      bf16x8 bl = ldb8(wih0l + (size_t)brow * 128 + ks * 32 + cg * 8);
      acc[nt] = __builtin_amdgcn_mfma_f32_16x16x32_bf16(ah, bh, acc[nt], 0, 0, 0);
      acc[nt] = __builtin_amdgcn_mfma_f32_16x16x32_bf16(ah, bl, acc[nt], 0, 0, 0);
      acc[nt] = __builtin_amdgcn_mfma_f32_16x16x32_bf16(al, bh, acc[nt], 0, 0, 0);
    }
  }
#pragma unroll
  for (int nt = 0; nt < 8; ++nt) {
#pragma unroll
    for (int r = 0; r < 4; ++r) {
      xg0[(size_t)(m0 + w * 16 + cg * 4 + r) * 512 + n0 + nt * 16 + l15] = acc[nt][r];
    }
  }
}

// ---------------------------------------------------------------------------
// Kernel 4: LSTM layer 0 -- K-sliced dot. Thread (ks=tid>>7, jj=tid&127)
// holds w[4 gates][32 k] (128 VGPR); per step only 8 broadcast b128 reads
// + 4 b32 partial writes. 128-thread tail combines (16 conflict-free b32
// reads), activates, updates c/h. 2 barriers/step.
// ---------------------------------------------------------------------------
__global__ __launch_bounds__(512) void k_lstm0(
    const float* __restrict__ xg0, const float* __restrict__ whh0T,
    const int* __restrict__ lengths, float* __restrict__ hs1) {
  __shared__ __align__(16) float h0s[H_];
  __shared__ float ps[16 * 128];  // [ks*4+q][jj]
  const int b = blockIdx.x;
  const int tid = threadIdx.x;
  const int ks = tid >> 7;   // 0..3 k-slice
  const int jj = tid & 127;
  float w[4][32];
#pragma unroll
  for (int kk = 0; kk < 32; ++kk) {
#pragma unroll
    for (int q = 0; q < 4; ++q)
      w[q][kk] = whh0T[(ks * 32 + kk) * 512 + q * 128 + jj];
  }
  if (tid < H_) h0s[tid] = 0.f;
  float c = 0.f;
  const int len = lengths[b];
  float xq0 = 0.f, xq1 = 0.f, xq2 = 0.f, xq3 = 0.f;
  if (tid < H_) {
    const float* xp = xg0 + (size_t)(b * T_) * 512;
    xq0 = xp[jj]; xq1 = xp[128 + jj]; xq2 = xp[256 + jj]; xq3 = xp[384 + jj];
  }
  __syncthreads();
  for (int t = 0; t < len; ++t) {
    float p0 = 0.f, p1 = 0.f, p2 = 0.f, p3 = 0.f;
#pragma unroll
    for (int k4 = 0; k4 < 8; ++k4) {
      float4 hv = *(const float4*)(h0s + ks * 32 + k4 * 4);
      p0 = fmaf(hv.x, w[0][k4 * 4], fmaf(hv.y, w[0][k4 * 4 + 1], fmaf(hv.z, w[0][k4 * 4 + 2], fmaf(hv.w, w[0][k4 * 4 + 3], p0))));
      p1 = fmaf(hv.x, w[1][k4 * 4], fmaf(hv.y, w[1][k4 * 4 + 1], fmaf(hv.z, w[1][k4 * 4 + 2], fmaf(hv.w, w[1][k4 * 4 + 3], p1))));
      p2 = fmaf(hv.x, w[2][k4 * 4], fmaf(hv.y, w[2][k4 * 4 + 1], fmaf(hv.z, w[2][k4 * 4 + 2], fmaf(hv.w, w[2][k4 * 4 + 3], p2))));
      p3 = fmaf(hv.x, w[3][k4 * 4], fmaf(hv.y, w[3][k4 * 4 + 1], fmaf(hv.z, w[3][k4 * 4 + 2], fmaf(hv.w, w[3][k4 * 4 + 3], p3))));
    }
    ps[(ks * 4 + 0) * 128 + jj] = p0;
    ps[(ks * 4 + 1) * 128 + jj] = p1;
    ps[(ks * 4 + 2) * 128 + jj] = p2;
    ps[(ks * 4 + 3) * 128 + jj] = p3;
    __syncthreads();
    if (tid < H_) {
      float gi = xq0 + ((ps[0 * 128 + jj] + ps[4 * 128 + jj]) + (ps[8 * 128 + jj] + ps[12 * 128 + jj]));
      float gf = xq1 + ((ps[1 * 128 + jj] + ps[5 * 128 + jj]) + (ps[9 * 128 + jj] + ps[13 * 128 + jj]));
      float gg = xq2 + ((ps[2 * 128 + jj] + ps[6 * 128 + jj]) + (ps[10 * 128 + jj] + ps[14 * 128 + jj]));
      float go = xq3 + ((ps[3 * 128 + jj] + ps[7 * 128 + jj]) + (ps[11 * 128 + jj] + ps[15 * 128 + jj]));
      float ig = sigmoidf_(gi);
      float fg = sigmoidf_(gf);
      float gt = tanhf(gg);
      float og = sigmoidf_(go);
      c = fg * c + ig * gt;
      float hn = og * tanhf(c);
      h0s[jj] = hn;
      hs1[((size_t)(b * T_ + t)) * H_ + jj] = hn;
      if (t + 1 < len) {
        const float* xp = xg0 + (size_t)(b * T_ + t + 1) * 512;
        xq0 = xp[jj]; xq1 = xp[128 + jj]; xq2 = xp[256 + jj]; xq3 = xp[384 + jj];
      }
    }
    __syncthreads();
  }
}

// ---------------------------------------------------------------------------
// Kernel 5: xg1 = hs1 @ wih1^T. (unchanged)
// ---------------------------------------------------------------------------
__global__ __launch_bounds__(512) void k_xg1(
    const float* __restrict__ hs1, const float* __restrict__ wih1T,
    float* __restrict__ xg1) {
  __shared__ __align__(16) float hsS[8][128];
  const int r0 = blockIdx.x * 8;
  const int tid = threadIdx.x;
  for (int i = tid; i < 8 * 128; i += 512) ((float*)hsS)[i] = hs1[(size_t)r0 * 128 + i];
  __syncthreads();
  float acc[8] = {0.f, 0.f, 0.f, 0.f, 0.f, 0.f, 0.f, 0.f};
#pragma unroll 4
  for (int k4 = 0; k4 < 32; ++k4) {
    float w0 = wih1T[(4 * k4 + 0) * 512 + tid];
    float w1v = wih1T[(4 * k4 + 1) * 512 + tid];
    float w2v = wih1T[(4 * k4 + 2) * 512 + tid];
    float w3v = wih1T[(4 * k4 + 3) * 512 + tid];
#pragma unroll
    for (int i = 0; i < 8; ++i) {
      float4 h = *(const float4*)(&hsS[i][4 * k4]);
      acc[i] += h.x * w0 + h.y * w1v + h.z * w2v + h.w * w3v;
    }
  }
#pragma unroll
  for (int i = 0; i < 8; ++i) xg1[((size_t)(r0 + i)) * 512 + tid] = acc[i];
}

// ---------------------------------------------------------------------------
// Kernel 6: LSTM layer 1 + FC tail -- same K-sliced structure.
// ---------------------------------------------------------------------------
__global__ __launch_bounds__(512) void k_lstm1(
    const float* __restrict__ xg1, const float* __restrict__ whh1T,
    const float* __restrict__ fc1, const float* __restrict__ fc2,
    const int* __restrict__ lengths, float* __restrict__ out) {
  __shared__ __align__(16) float h1s[H_];
  __shared__ float ps[16 * 128];
  __shared__ float tmp10[10];
  const int b = blockIdx.x;
  const int tid = threadIdx.x;
  const int ks = tid >> 7;
  const int jj = tid & 127;
  float w[4][32];
#pragma unroll
  for (int kk = 0; kk < 32; ++kk) {
#pragma unroll
    for (int q = 0; q < 4; ++q)
      w[q][kk] = whh1T[(ks * 32 + kk) * 512 + q * 128 + jj];
  }
  if (tid < H_) h1s[tid] = 0.f;
  float c = 0.f;
  const int len = lengths[b];
  float xq0 = 0.f, xq1 = 0.f, xq2 = 0.f, xq3 = 0.f;
  if (tid < H_) {
    const float* xp = xg1 + (size_t)(b * T_) * 512;
    xq0 = xp[jj]; xq1 = xp[128 + jj]; xq2 = xp[256 + jj]; xq3 = xp[384 + jj];
  }
  __syncthreads();
  for (int t = 0; t < len; ++t) {
    float p0 = 0.f, p1 = 0.f, p2 = 0.f, p3 = 0.f;
#pragma unroll
    for (int k4 = 0; k4 < 8; ++k4) {
      float4 hv = *(const float4*)(h1s + ks * 32 + k4 * 4);
      p0 = fmaf(hv.x, w[0][k4 * 4], fmaf(hv.y, w[0][k4 * 4 + 1], fmaf(hv.z, w[0][k4 * 4 + 2], fmaf(hv.w, w[0][k4 * 4 + 3], p0))));
      p1 = fmaf(hv.x, w[1][k4 * 4], fmaf(hv.y, w[1][k4 * 4 + 1], fmaf(hv.z, w[1][k4 * 4 + 2], fmaf(hv.w, w[1][k4 * 4 + 3], p1))));
      p2 = fmaf(hv.x, w[2][k4 * 4], fmaf(hv.y, w[2][k4 * 4 + 1], fmaf(hv.z, w[2][k4 * 4 + 2], fmaf(hv.w, w[2][k4 * 4 + 3], p2))));
      p3 = fmaf(hv.x, w[3][k4 * 4], fmaf(hv.y, w[3][k4 * 4 + 1], fmaf(hv.z, w[3][k4 * 4 + 2], fmaf(hv.w, w[3][k4 * 4 + 3], p3))));
    }
    ps[(ks * 4 + 0) * 128 + jj] = p0;
    ps[(ks * 4 + 1) * 128 + jj] = p1;
    ps[(ks * 4 + 2) * 128 + jj] = p2;
    ps[(ks * 4 + 3) * 128 + jj] = p3;
    __syncthreads();
    if (tid < H_) {
      float gi = xq0 + ((ps[0 * 128 + jj] + ps[4 * 128 + jj]) + (ps[8 * 128 + jj] + ps[12 * 128 + jj]));
      float gf = xq1 + ((ps[1 * 128 + jj] + ps[5 * 128 + jj]) + (ps[9 * 128 + jj] + ps[13 * 128 + jj]));
      float gg = xq2 + ((ps[2 * 128 + jj] + ps[6 * 128 + jj]) + (ps[10 * 128 + jj] + ps[14 * 128 + jj]));
      float go = xq3 + ((ps[3 * 128 + jj] + ps[7 * 128 + jj]) + (ps[11 * 128 + jj] + ps[15 * 128 + jj]));
      float ig = sigmoidf_(gi);
      float fg = sigmoidf_(gf);
      float gt = tanhf(gg);
      float og = sigmoidf_(go);
      c = fg * c + ig * gt;
      float hn = og * tanhf(c);
      h1s[jj] = hn;
      if (t + 1 < len) {
        const float* xp = xg1 + (size_t)(b * T_ + t + 1) * 512;
        xq0 = xp[jj]; xq1 = xp[128 + jj]; xq2 = xp[256 + jj]; xq3 = xp[384 + jj];
      }
    }
    __syncthreads();
  }
  if (tid < 10) {
    const float* fr = fc1 + tid * H_;
    float s = 0.f;
#pragma unroll 4
    for (int k = 0; k < H_; ++k) s += h1s[k] * fr[k];
    tmp10[tid] = leakyf(s);
  }
  __syncthreads();
  if (tid < 2) {
    const float* fr = fc2 + tid * 10;
    float s = 0.f;
#pragma unroll
    for (int j = 0; j < 10; ++j) s += tmp10[j] * fr[j];
    out[b * 2 + tid] = leakyf(s);
  }
}

extern "C" void kernel_launch(void* const* d_in, const int* in_sizes, int n_in,
                              void* d_out, int out_size, void* d_ws, size_t ws_size,
                              hipStream_t stream) {
  const float* X = (const float*)d_in[0];
  const int* lengths = (const int*)d_in[1];
  const float* w1 = (const float*)d_in[2];
  const float* w2 = (const float*)d_in[3];
  const float* w3 = (const float*)d_in[4];
  const float* linw = (const float*)d_in[5];
  const float* wih0 = (const float*)d_in[6];
  const float* whh0 = (const float*)d_in[7];
  const float* wih1 = (const float*)d_in[8];
  const float* whh1 = (const float*)d_in[9];
  const float* fc1 = (const float*)d_in[10];
  const float* fc2 = (const float*)d_in[11];

  char* wsb = (char*)d_ws;
  size_t off = 0;
  auto alloc = [&](size_t bytes) {
    char* p = wsb + off;
    off += (bytes + 511) & ~(size_t)511;
    return p;
  };
  unsigned short* s3g = (unsigned short*)alloc(2048 * 1728 * 2);
  unsigned short* feh = (unsigned short*)alloc(2048 * 128 * 2);
  unsigned short* fel = (unsigned short*)alloc(2048 * 128 * 2);
  float* xg0 = (float*)alloc(2048 * 512 * 4);
  unsigned short* w1eh = (unsigned short*)alloc(1024 * 2);
  unsigned short* w1el = (unsigned short*)alloc(1024 * 2);
  unsigned short* w2h = (unsigned short*)alloc(20480 * 2);
  unsigned short* w2l = (unsigned short*)alloc(20480 * 2);
  unsigned short* w3h = (unsigned short*)alloc(5120 * 2);
  unsigned short* w3l = (unsigned short*)alloc(5120 * 2);
  unsigned short* linwh = (unsigned short*)alloc(172800 * 2);
  unsigned short* linwl = (unsigned short*)alloc(172800 * 2);
  unsigned short* wih0h = (unsigned short*)alloc(65536 * 2);
  unsigned short* wih0l = (unsigned short*)alloc(65536 * 2);
  float* whh0T = (float*)alloc(65536 * 4);
  float* wih1T = (float*)alloc(65536 * 4);
  float* whh1T = (float*)alloc(65536 * 4);
  float* hs1 = (float*)alloc(262144 * 4);
  float* xg1 = (float*)alloc(2048 * 512 * 4);

  k_prep<<<1803, 256, 0, stream>>>(w1, w2, w3, linw, wih0, whh0, wih1, whh1,
                                   w1eh, w1el, w2h, w2l, w3h, w3l,
                                   linwh, linwl, wih0h, wih0l,
                                   whh0T, wih1T, whh1T);
  k_conv123<<<2048, 512, 0, stream>>>(X, w1, w2h, w2l, w3h, w3l, s3g);
  k_gemm_fe<<<128, 448, 0, stream>>>(s3g, linwh, linwl, feh, fel);
  k_gemm_xg0<<<dim3(32, 4), 256, 0, stream>>>(feh, fel, wih0h, wih0l, xg0);
  k_lstm0<<<32, 512, 0, stream>>>(xg0, whh0T, lengths, hs1);
  k_xg1<<<256, 512, 0, stream>>>(hs1, wih1T, xg1);
  k_lstm1<<<32, 512, 0, stream>>>(xg1, whh1T, fc1, fc2, lengths, (float*)d_out);
}

// Round 10
// 284.165 us; speedup vs baseline: 1.3346x; 1.0445x over previous
//
#include <hip/hip_runtime.h>
#include <hip/hip_bf16.h>

#define B_ 32
#define T_ 64
#define H_ 128
#define L3OUT 54
#define FLAT_ 1728

typedef __attribute__((ext_vector_type(8))) short bf16x8;
typedef __attribute__((ext_vector_type(4))) float f32x4;

__device__ __forceinline__ float leakyf(float v) { return v > 0.f ? v : 0.01f * v; }
__device__ __forceinline__ float sigmoidf_(float v) { return 1.f / (1.f + expf(-v)); }
__device__ __forceinline__ unsigned int bf16rne(float v) {
  unsigned int b = __float_as_uint(v);
  return (b + 0x7FFFu + ((b >> 16) & 1u)) >> 16;
}
__device__ __forceinline__ bf16x8 ldb8(const unsigned short* p) {
  return *(const bf16x8*)p;
}

// ---------------------------------------------------------------------------
// Kernel 0: weight prep + transposes. (unchanged)
// ---------------------------------------------------------------------------
__global__ __launch_bounds__(256) void k_prep(
    const float* __restrict__ w1, const float* __restrict__ w2,
    const float* __restrict__ w3, const float* __restrict__ linw,
    const float* __restrict__ wih0, const float* __restrict__ whh0,
    const float* __restrict__ wih1, const float* __restrict__ whh1,
    unsigned short* __restrict__ w1eh, unsigned short* __restrict__ w1el,
    unsigned short* __restrict__ w2h, unsigned short* __restrict__ w2l,
    unsigned short* __restrict__ w3h, unsigned short* __restrict__ w3l,
    unsigned short* __restrict__ linwh, unsigned short* __restrict__ linwl,
    unsigned short* __restrict__ wih0h, unsigned short* __restrict__ wih0l,
    float* __restrict__ whh0T, float* __restrict__ wih1T,
    float* __restrict__ whh1T) {
  const int e = blockIdx.x * 256 + threadIdx.x;
  if (e >= 264960) {
    int e5 = e - 264960;
    int m = e5 >> 16, r = e5 & 65535;
    int k = r >> 9, j = r & 511;
    const float* src = (m == 0) ? whh0 : ((m == 1) ? wih1 : whh1);
    float* dst = (m == 0) ? whh0T : ((m == 1) ? wih1T : whh1T);
    dst[r] = src[j * 128 + k];
    return;
  }
  float v;
  unsigned short* dh;
  unsigned short* dl;
  int di;
  if (e < 20480) {
    int cc = e / 5120, rem = e - cc * 5120;
    int c2 = rem / 160, r = rem - c2 * 160;
    int tap = r >> 5, c1l = r & 31;
    v = w2[c2 * 640 + (cc * 32 + c1l) * 5 + tap];
    dh = w2h; dl = w2l; di = e;
  } else if (e < 25600) {
    int e2 = e - 20480;
    int c3 = e2 / 160, r = e2 - c3 * 160;
    int tap = r >> 5, c2 = r & 31;
    v = w3[c3 * 160 + c2 * 5 + tap];
    dh = w3h; dl = w3l; di = e2;
  } else if (e < 198400) {
    int e3 = e - 25600;
    v = linw[e3];
    dh = linwh; dl = linwl; di = e3;
  } else if (e < 263936) {
    int e4 = e - 198400;
    int g = e4 >> 7, k = e4 & 127;
    v = (k < 100) ? wih0[g * 100 + k] : 0.f;
    dh = wih0h; dl = wih0l; di = e4;
  } else {
    int i = e - 263936;
    int c1 = i >> 3, j = i & 7;
    v = (j < 5) ? w1[c1 * 5 + j] : 0.f;
    dh = w1eh; dl = w1el; di = i;
  }
  unsigned int hb = bf16rne(v);
  float hf = __uint_as_float(hb << 16);
  unsigned int lb = bf16rne(v - hf);
  dh[di] = (unsigned short)hb;
  dl[di] = (unsigned short)lb;
}

// ---------------------------------------------------------------------------
// Kernel 1: conv1 (fp32, thread=position) + conv2 (MFMA) + conv3 (MFMA).
// One block per n, 512 threads, 48.6 KB LDS -> 3 blocks/CU.
// conv1 NEW: thread = position (0..499). Window (5 floats) read from Xs ONCE
// (hoisted out of the chunk loop); weights via wave-uniform s_load; all 32 c1
// computed in registers; row written as 4x ds_write_b128 (lane word-stride 20:
// 8 lanes cover all 32 banks -> conflict-free). LDS instrs/chunk ~7x lower.
// conv2/conv3: round-6 verified structure, unswizzled.
// ---------------------------------------------------------------------------
__global__ __launch_bounds__(512) void k_conv123(
    const float* __restrict__ X, const float* __restrict__ w1,
    const unsigned short* __restrict__ w2h, const unsigned short* __restrict__ w2l,
    const unsigned short* __restrict__ w3h, const unsigned short* __restrict__ w3l,
    unsigned short* __restrict__ s3g) {
  __shared__ __align__(16) float Xs[1504];
  __shared__ __align__(16) unsigned int AhU[10640];  // [532 rows][20 u32]

  const int n = blockIdx.x;
  const int tid = threadIdx.x;
  const int lane = tid & 63;
  const int w = tid >> 6;        // 0..7
  const int l15 = lane & 15;
  const int cg = lane >> 4;

  const float* Xn = X + (size_t)n * 1500;
  for (int i = tid; i < 1500; i += 512) Xs[i] = Xn[i];
  if (tid < 4) Xs[1500 + tid] = 0.f;
  for (int i = tid; i < 640; i += 512) AhU[10000 + i] = 0u;  // rows 500..531
  __syncthreads();

  // hoisted conv1 window (position = tid)
  float x0 = 0.f, x1 = 0.f, x2 = 0.f, x3 = 0.f, x4 = 0.f;
  if (tid < 500) {
    const float* xp = Xs + 3 * tid;
    x0 = xp[0]; x1 = xp[1]; x2 = xp[2]; x3 = xp[3]; x4 = xp[4];
  }

  f32x4 acc2[2][2];
#pragma unroll
  for (int a = 0; a < 2; ++a)
#pragma unroll
    for (int m = 0; m < 2; ++m) acc2[a][m] = (f32x4){0.f, 0.f, 0.f, 0.f};

  for (int cc = 0; cc < 4; ++cc) {  // 4 chunks of 32 c1
    __syncthreads();                // previous chunk's conv2 reads done
    // ---- conv1: all 32 c1 of this chunk for position tid ----
    if (tid < 500) {
      const float* wc = w1 + cc * 160;  // uniform address -> s_load
      unsigned int rowbuf[16];
#pragma unroll
      for (int p = 0; p < 16; ++p) {
        const float* wa = wc + 10 * p;
        float vA = fmaf(x4, wa[4], fmaf(x3, wa[3], fmaf(x2, wa[2], fmaf(x1, wa[1], x0 * wa[0]))));
        float vB = fmaf(x4, wa[9], fmaf(x3, wa[8], fmaf(x2, wa[7], fmaf(x1, wa[6], x0 * wa[5]))));
        vA = fmaxf(vA, 0.01f * vA);  // leaky == max(v, 0.01v)
        vB = fmaxf(vB, 0.01f * vB);
        rowbuf[p] = bf16rne(vA) | (bf16rne(vB) << 16);
      }
#pragma unroll
      for (int q = 0; q < 4; ++q)
        *(uint4*)(&AhU[tid * 20 + 4 * q]) = *(uint4*)(&rowbuf[4 * q]);
    }
    __syncthreads();
    // ---- conv2 MFMA over this chunk ----
    const unsigned short* w2hB = w2h + cc * 5120;
    const unsigned short* w2lB = w2l + cc * 5120;
#pragma unroll
    for (int tap = 0; tap < 5; ++tap) {
      const int wc = tap * 32 + cg * 8;
      bf16x8 ah0 = ldb8(w2hB + l15 * 160 + wc);
      bf16x8 ah1 = ldb8(w2hB + (l15 + 16) * 160 + wc);
      bf16x8 al0 = ldb8(w2lB + l15 * 160 + wc);
      bf16x8 al1 = ldb8(w2lB + (l15 + 16) * 160 + wc);
      {  // n-tile w
        bf16x8 bfr = ldb8((const unsigned short*)AhU + (3 * (w * 16 + l15) + tap) * 40 + cg * 8);
        acc2[0][0] = __builtin_amdgcn_mfma_f32_16x16x32_bf16(ah0, bfr, acc2[0][0], 0, 0, 0);
        acc2[0][0] = __builtin_amdgcn_mfma_f32_16x16x32_bf16(al0, bfr, acc2[0][0], 0, 0, 0);
        acc2[0][1] = __builtin_amdgcn_mfma_f32_16x16x32_bf16(ah1, bfr, acc2[0][1], 0, 0, 0);
        acc2[0][1] = __builtin_amdgcn_mfma_f32_16x16x32_bf16(al1, bfr, acc2[0][1], 0, 0, 0);
      }
      if (w < 3) {  // n-tile 8+w
        int nt = 8 + w;
        bf16x8 bfr = ldb8((const unsigned short*)AhU + (3 * (nt * 16 + l15) + tap) * 40 + cg * 8);
        acc2[1][0] = __builtin_amdgcn_mfma_f32_16x16x32_bf16(ah0, bfr, acc2[1][0], 0, 0, 0);
        acc2[1][0] = __builtin_amdgcn_mfma_f32_16x16x32_bf16(al0, bfr, acc2[1][0], 0, 0, 0);
        acc2[1][1] = __builtin_amdgcn_mfma_f32_16x16x32_bf16(ah1, bfr, acc2[1][1], 0, 0, 0);
        acc2[1][1] = __builtin_amdgcn_mfma_f32_16x16x32_bf16(al1, bfr, acc2[1][1], 0, 0, 0);
      }
    }
  }
  __syncthreads();  // all conv2 reads of AhU done
  // A3 (aliases AhU): rows = l2; zero pad rows 176..195
  for (int i = tid; i < 400; i += 512) AhU[176 * 20 + i] = 0u;
#pragma unroll
  for (int nti = 0; nti < 2; ++nti) {
    int nt = (nti == 0) ? w : (8 + w);
    if (nti == 0 || w < 3) {
      int l2 = nt * 16 + l15;
#pragma unroll
      for (int mt = 0; mt < 2; ++mt) {
#pragma unroll
        for (int j = 0; j < 2; ++j) {
          float e0 = leakyf(acc2[nti][mt][2 * j]);
          float e1 = leakyf(acc2[nti][mt][2 * j + 1]);
          AhU[l2 * 20 + mt * 8 + cg * 2 + j] = bf16rne(e0) | (bf16rne(e1) << 16);
        }
      }
    }
  }
  __syncthreads();
  // conv3 MFMA: waves 0..3 (l3 tile = w)
  if (w < 4) {
    f32x4 a3[2];
    a3[0] = (f32x4){0.f, 0.f, 0.f, 0.f};
    a3[1] = (f32x4){0.f, 0.f, 0.f, 0.f};
#pragma unroll
    for (int tap = 0; tap < 5; ++tap) {
      const int wc = tap * 32 + cg * 8;
      bf16x8 wh0 = ldb8(w3h + l15 * 160 + wc);
      bf16x8 wh1 = ldb8(w3h + (l15 + 16) * 160 + wc);
      bf16x8 wl0 = ldb8(w3l + l15 * 160 + wc);
      bf16x8 wl1 = ldb8(w3l + (l15 + 16) * 160 + wc);
      bf16x8 bfr = ldb8((const unsigned short*)AhU + (3 * (w * 16 + l15) + tap) * 40 + cg * 8);
      a3[0] = __builtin_amdgcn_mfma_f32_16x16x32_bf16(wh0, bfr, a3[0], 0, 0, 0);
      a3[0] = __builtin_amdgcn_mfma_f32_16x16x32_bf16(wl0, bfr, a3[0], 0, 0, 0);
      a3[1] = __builtin_amdgcn_mfma_f32_16x16x32_bf16(wh1, bfr, a3[1], 0, 0, 0);
      a3[1] = __builtin_amdgcn_mfma_f32_16x16x32_bf16(wl1, bfr, a3[1], 0, 0, 0);
    }
    int l3 = w * 16 + l15;
    if (l3 < L3OUT) {
#pragma unroll
      for (int mt = 0; mt < 2; ++mt) {
#pragma unroll
        for (int r = 0; r < 4; ++r) {
          int c3 = mt * 16 + cg * 4 + r;
          s3g[(size_t)n * FLAT_ + c3 * L3OUT + l3] = (unsigned short)bf16rne(leakyf(a3[mt][r]));
        }
      }
    }
  }
}

// ---------------------------------------------------------------------------
// Kernel 2: FUSED fe + xg0. 128 blocks (16 samples each) x 448 thr.
// Phase 1 (== old k_gemm_fe): fe[16][112] via global-direct MFMA, K=1728.
//   fe hi/lo -> LDS [16][136] (pad 136: row stride 68 words == 4 mod 32 ->
//   2 lanes/bank). K-pad cols 112..135 zeroed (finite; x zero wih0 pad = 0).
// Phase 2 (== old k_gemm_xg0): xg0 tile [16][512], 3-pass hi/lo, B from L2.
// ---------------------------------------------------------------------------
__global__ __launch_bounds__(448) void k_gemm_fx(
    const unsigned short* __restrict__ s3g,
    const unsigned short* __restrict__ linwh, const unsigned short* __restrict__ linwl,
    const unsigned short* __restrict__ wih0h, const unsigned short* __restrict__ wih0l,
    float* __restrict__ xg0) {
  __shared__ __align__(16) unsigned short fehS[16][136];
  __shared__ __align__(16) unsigned short felS[16][136];

  const int m0 = blockIdx.x * 16;
  const int tid = threadIdx.x;
  const int lane = tid & 63;
  const int w = tid >> 6;  // 0..6
  const int l15 = lane & 15;
  const int cg = lane >> 4;

  // zero K-pad cols 112..135 (NaN x 0 hazard in phase 2)
  if (tid < 192) {
    int r = tid / 12, c = tid - r * 12;
    ((unsigned int*)&fehS[r][112])[c] = 0u;
    ((unsigned int*)&felS[r][112])[c] = 0u;
  }

  int brow = w * 16 + l15;
  if (brow > 99) brow = 99;
  const unsigned short* ap = s3g + (size_t)(m0 + l15) * FLAT_ + cg * 8;
  const unsigned short* bhp = linwh + (size_t)brow * FLAT_ + cg * 8;
  const unsigned short* blp = linwl + (size_t)brow * FLAT_ + cg * 8;

  f32x4 acc = (f32x4){0.f, 0.f, 0.f, 0.f};
#pragma unroll 6
  for (int ks = 0; ks < 54; ++ks) {
    bf16x8 af = ldb8(ap + ks * 32);
    bf16x8 bh = ldb8(bhp + ks * 32);
    bf16x8 bl = ldb8(blp + ks * 32);
    acc = __builtin_amdgcn_mfma_f32_16x16x32_bf16(af, bh, acc, 0, 0, 0);
    acc = __builtin_amdgcn_mfma_f32_16x16x32_bf16(af, bl, acc, 0, 0, 0);
  }
  const int jcol = w * 16 + l15;
#pragma unroll
  for (int r = 0; r < 4; ++r) {
    float v = acc[r];
    unsigned int hb = bf16rne(v);
    float hf = __uint_as_float(hb << 16);
    unsigned int lb = bf16rne(v - hf);
    fehS[cg * 4 + r][jcol] = (unsigned short)hb;
    felS[cg * 4 + r][jcol] = (unsigned short)lb;
  }
  __syncthreads();

  // phase 2: xg0[m0..m0+15][512]; wave w handles n-tiles w, w+7, w+14, ...
#pragma unroll
  for (int nt0 = 0; nt0 < 5; ++nt0) {
    int nt = w + 7 * nt0;
    if (nt < 32) {
      f32x4 a = (f32x4){0.f, 0.f, 0.f, 0.f};
#pragma unroll
      for (int ks = 0; ks < 4; ++ks) {
        bf16x8 ah = ldb8(&fehS[l15][ks * 32 + cg * 8]);
        bf16x8 al = ldb8(&felS[l15][ks * 32 + cg * 8]);
        int br = nt * 16 + l15;
        bf16x8 bh = ldb8(wih0h + (size_t)br * 128 + ks * 32 + cg * 8);
        bf16x8 bl = ldb8(wih0l + (size_t)br * 128 + ks * 32 + cg * 8);
        a = __builtin_amdgcn_mfma_f32_16x16x32_bf16(ah, bh, a, 0, 0, 0);
        a = __builtin_amdgcn_mfma_f32_16x16x32_bf16(ah, bl, a, 0, 0, 0);
        a = __builtin_amdgcn_mfma_f32_16x16x32_bf16(al, bh, a, 0, 0, 0);
      }
#pragma unroll
      for (int r = 0; r < 4; ++r)
        xg0[(size_t)(m0 + cg * 4 + r) * 512 + nt * 16 + l15] = a[r];
    }
  }
}

// ---------------------------------------------------------------------------
// Kernel 3: LSTM layer 0 -- K-sliced dot. (unchanged from round 9)
// ---------------------------------------------------------------------------
__global__ __launch_bounds__(512) void k_lstm0(
    const float* __restrict__ xg0, const float* __restrict__ whh0T,
    const int* __restrict__ lengths, float* __restrict__ hs1) {
  __shared__ __align__(16) float h0s[H_];
  __shared__ float ps[16 * 128];
  const int b = blockIdx.x;
  const int tid = threadIdx.x;
  const int ks = tid >> 7;
  const int jj = tid & 127;
  float w[4][32];
#pragma unroll
  for (int kk = 0; kk < 32; ++kk) {
#pragma unroll
    for (int q = 0; q < 4; ++q)
      w[q][kk] = whh0T[(ks * 32 + kk) * 512 + q * 128 + jj];
  }
  if (tid < H_) h0s[tid] = 0.f;
  float c = 0.f;
  const int len = lengths[b];
  float xq0 = 0.f, xq1 = 0.f, xq2 = 0.f, xq3 = 0.f;
  if (tid < H_) {
    const float* xp = xg0 + (size_t)(b * T_) * 512;
    xq0 = xp[jj]; xq1 = xp[128 + jj]; xq2 = xp[256 + jj]; xq3 = xp[384 + jj];
  }
  __syncthreads();
  for (int t = 0; t < len; ++t) {
    float p0 = 0.f, p1 = 0.f, p2 = 0.f, p3 = 0.f;
#pragma unroll
    for (int k4 = 0; k4 < 8; ++k4) {
      float4 hv = *(const float4*)(h0s + ks * 32 + k4 * 4);
      p0 = fmaf(hv.x, w[0][k4 * 4], fmaf(hv.y, w[0][k4 * 4 + 1], fmaf(hv.z, w[0][k4 * 4 + 2], fmaf(hv.w, w[0][k4 * 4 + 3], p0))));
      p1 = fmaf(hv.x, w[1][k4 * 4], fmaf(hv.y, w[1][k4 * 4 + 1], fmaf(hv.z, w[1][k4 * 4 + 2], fmaf(hv.w, w[1][k4 * 4 + 3], p1))));
      p2 = fmaf(hv.x, w[2][k4 * 4], fmaf(hv.y, w[2][k4 * 4 + 1], fmaf(hv.z, w[2][k4 * 4 + 2], fmaf(hv.w, w[2][k4 * 4 + 3], p2))));
      p3 = fmaf(hv.x, w[3][k4 * 4], fmaf(hv.y, w[3][k4 * 4 + 1], fmaf(hv.z, w[3][k4 * 4 + 2], fmaf(hv.w, w[3][k4 * 4 + 3], p3))));
    }
    ps[(ks * 4 + 0) * 128 + jj] = p0;
    ps[(ks * 4 + 1) * 128 + jj] = p1;
    ps[(ks * 4 + 2) * 128 + jj] = p2;
    ps[(ks * 4 + 3) * 128 + jj] = p3;
    __syncthreads();
    if (tid < H_) {
      float gi = xq0 + ((ps[0 * 128 + jj] + ps[4 * 128 + jj]) + (ps[8 * 128 + jj] + ps[12 * 128 + jj]));
      float gf = xq1 + ((ps[1 * 128 + jj] + ps[5 * 128 + jj]) + (ps[9 * 128 + jj] + ps[13 * 128 + jj]));
      float gg = xq2 + ((ps[2 * 128 + jj] + ps[6 * 128 + jj]) + (ps[10 * 128 + jj] + ps[14 * 128 + jj]));
      float go = xq3 + ((ps[3 * 128 + jj] + ps[7 * 128 + jj]) + (ps[11 * 128 + jj] + ps[15 * 128 + jj]));
      float ig = sigmoidf_(gi);
      float fg = sigmoidf_(gf);
      float gt = tanhf(gg);
      float og = sigmoidf_(go);
      c = fg * c + ig * gt;
      float hn = og * tanhf(c);
      h0s[jj] = hn;
      hs1[((size_t)(b * T_ + t)) * H_ + jj] = hn;
      if (t + 1 < len) {
        const float* xp = xg0 + (size_t)(b * T_ + t + 1) * 512;
        xq0 = xp[jj]; xq1 = xp[128 + jj]; xq2 = xp[256 + jj]; xq3 = xp[384 + jj];
      }
    }
    __syncthreads();
  }
}

// ---------------------------------------------------------------------------
// Kernel 4: xg1 = hs1 @ wih1^T. (unchanged)
// ---------------------------------------------------------------------------
__global__ __launch_bounds__(512) void k_xg1(
    const float* __restrict__ hs1, const float* __restrict__ wih1T,
    float* __restrict__ xg1) {
  __shared__ __align__(16) float hsS[8][128];
  const int r0 = blockIdx.x * 8;
  const int tid = threadIdx.x;
  for (int i = tid; i < 8 * 128; i += 512) ((float*)hsS)[i] = hs1[(size_t)r0 * 128 + i];
  __syncthreads();
  float acc[8] = {0.f, 0.f, 0.f, 0.f, 0.f, 0.f, 0.f, 0.f};
#pragma unroll 4
  for (int k4 = 0; k4 < 32; ++k4) {
    float w0 = wih1T[(4 * k4 + 0) * 512 + tid];
    float w1v = wih1T[(4 * k4 + 1) * 512 + tid];
    float w2v = wih1T[(4 * k4 + 2) * 512 + tid];
    float w3v = wih1T[(4 * k4 + 3) * 512 + tid];
#pragma unroll
    for (int i = 0; i < 8; ++i) {
      float4 h = *(const float4*)(&hsS[i][4 * k4]);
      acc[i] += h.x * w0 + h.y * w1v + h.z * w2v + h.w * w3v;
    }
  }
#pragma unroll
  for (int i = 0; i < 8; ++i) xg1[((size_t)(r0 + i)) * 512 + tid] = acc[i];
}

// ---------------------------------------------------------------------------
// Kernel 5: LSTM layer 1 + FC tail. (unchanged from round 9)
// ---------------------------------------------------------------------------
__global__ __launch_bounds__(512) void k_lstm1(
    const float* __restrict__ xg1, const float* __restrict__ whh1T,
    const float* __restrict__ fc1, const float* __restrict__ fc2,
    const int* __restrict__ lengths, float* __restrict__ out) {
  __shared__ __align__(16) float h1s[H_];
  __shared__ float ps[16 * 128];
  __shared__ float tmp10[10];
  const int b = blockIdx.x;
  const int tid = threadIdx.x;
  const int ks = tid >> 7;
  const int jj = tid & 127;
  float w[4][32];
#pragma unroll
  for (int kk = 0; kk < 32; ++kk) {
#pragma unroll
    for (int q = 0; q < 4; ++q)
      w[q][kk] = whh1T[(ks * 32 + kk) * 512 + q * 128 + jj];
  }
  if (tid < H_) h1s[tid] = 0.f;
  float c = 0.f;
  const int len = lengths[b];
  float xq0 = 0.f, xq1 = 0.f, xq2 = 0.f, xq3 = 0.f;
  if (tid < H_) {
    const float* xp = xg1 + (size_t)(b * T_) * 512;
    xq0 = xp[jj]; xq1 = xp[128 + jj]; xq2 = xp[256 + jj]; xq3 = xp[384 + jj];
  }
  __syncthreads();
  for (int t = 0; t < len; ++t) {
    float p0 = 0.f, p1 = 0.f, p2 = 0.f, p3 = 0.f;
#pragma unroll
    for (int k4 = 0; k4 < 8; ++k4) {
      float4 hv = *(const float4*)(h1s + ks * 32 + k4 * 4);
      p0 = fmaf(hv.x, w[0][k4 * 4], fmaf(hv.y, w[0][k4 * 4 + 1], fmaf(hv.z, w[0][k4 * 4 + 2], fmaf(hv.w, w[0][k4 * 4 + 3], p0))));
      p1 = fmaf(hv.x, w[1][k4 * 4], fmaf(hv.y, w[1][k4 * 4 + 1], fmaf(hv.z, w[1][k4 * 4 + 2], fmaf(hv.w, w[1][k4 * 4 + 3], p1))));
      p2 = fmaf(hv.x, w[2][k4 * 4], fmaf(hv.y, w[2][k4 * 4 + 1], fmaf(hv.z, w[2][k4 * 4 + 2], fmaf(hv.w, w[2][k4 * 4 + 3], p2))));
      p3 = fmaf(hv.x, w[3][k4 * 4], fmaf(hv.y, w[3][k4 * 4 + 1], fmaf(hv.z, w[3][k4 * 4 + 2], fmaf(hv.w, w[3][k4 * 4 + 3], p3))));
    }
    ps[(ks * 4 + 0) * 128 + jj] = p0;
    ps[(ks * 4 + 1) * 128 + jj] = p1;
    ps[(ks * 4 + 2) * 128 + jj] = p2;
    ps[(ks * 4 + 3) * 128 + jj] = p3;
    __syncthreads();
    if (tid < H_) {
      float gi = xq0 + ((ps[0 * 128 + jj] + ps[4 * 128 + jj]) + (ps[8 * 128 + jj] + ps[12 * 128 + jj]));
      float gf = xq1 + ((ps[1 * 128 + jj] + ps[5 * 128 + jj]) + (ps[9 * 128 + jj] + ps[13 * 128 + jj]));
      float gg = xq2 + ((ps[2 * 128 + jj] + ps[6 * 128 + jj]) + (ps[10 * 128 + jj] + ps[14 * 128 + jj]));
      float go = xq3 + ((ps[3 * 128 + jj] + ps[7 * 128 + jj]) + (ps[11 * 128 + jj] + ps[15 * 128 + jj]));
      float ig = sigmoidf_(gi);
      float fg = sigmoidf_(gf);
      float gt = tanhf(gg);
      float og = sigmoidf_(go);
      c = fg * c + ig * gt;
      float hn = og * tanhf(c);
      h1s[jj] = hn;
      if (t + 1 < len) {
        const float* xp = xg1 + (size_t)(b * T_ + t + 1) * 512;
        xq0 = xp[jj]; xq1 = xp[128 + jj]; xq2 = xp[256 + jj]; xq3 = xp[384 + jj];
      }
    }
    __syncthreads();
  }
  if (tid < 10) {
    const float* fr = fc1 + tid * H_;
    float s = 0.f;
#pragma unroll 4
    for (int k = 0; k < H_; ++k) s += h1s[k] * fr[k];
    tmp10[tid] = leakyf(s);
  }
  __syncthreads();
  if (tid < 2) {
    const float* fr = fc2 + tid * 10;
    float s = 0.f;
#pragma unroll
    for (int j = 0; j < 10; ++j) s += tmp10[j] * fr[j];
    out[b * 2 + tid] = leakyf(s);
  }
}

extern "C" void kernel_launch(void* const* d_in, const int* in_sizes, int n_in,
                              void* d_out, int out_size, void* d_ws, size_t ws_size,
                              hipStream_t stream) {
  const float* X = (const float*)d_in[0];
  const int* lengths = (const int*)d_in[1];
  const float* w1 = (const float*)d_in[2];
  const float* w2 = (const float*)d_in[3];
  const float* w3 = (const float*)d_in[4];
  const float* linw = (const float*)d_in[5];
  const float* wih0 = (const float*)d_in[6];
  const float* whh0 = (const float*)d_in[7];
  const float* wih1 = (const float*)d_in[8];
  const float* whh1 = (const float*)d_in[9];
  const float* fc1 = (const float*)d_in[10];
  const float* fc2 = (const float*)d_in[11];

  char* wsb = (char*)d_ws;
  size_t off = 0;
  auto alloc = [&](size_t bytes) {
    char* p = wsb + off;
    off += (bytes + 511) & ~(size_t)511;
    return p;
  };
  unsigned short* s3g = (unsigned short*)alloc(2048 * 1728 * 2);
  float* xg0 = (float*)alloc(2048 * 512 * 4);
  unsigned short* w1eh = (unsigned short*)alloc(1024 * 2);
  unsigned short* w1el = (unsigned short*)alloc(1024 * 2);
  unsigned short* w2h = (unsigned short*)alloc(20480 * 2);
  unsigned short* w2l = (unsigned short*)alloc(20480 * 2);
  unsigned short* w3h = (unsigned short*)alloc(5120 * 2);
  unsigned short* w3l = (unsigned short*)alloc(5120 * 2);
  unsigned short* linwh = (unsigned short*)alloc(172800 * 2);
  unsigned short* linwl = (unsigned short*)alloc(172800 * 2);
  unsigned short* wih0h = (unsigned short*)alloc(65536 * 2);
  unsigned short* wih0l = (unsigned short*)alloc(65536 * 2);
  float* whh0T = (float*)alloc(65536 * 4);
  float* wih1T = (float*)alloc(65536 * 4);
  float* whh1T = (float*)alloc(65536 * 4);
  float* hs1 = (float*)alloc(262144 * 4);
  float* xg1 = (float*)alloc(2048 * 512 * 4);

  k_prep<<<1803, 256, 0, stream>>>(w1, w2, w3, linw, wih0, whh0, wih1, whh1,
                                   w1eh, w1el, w2h, w2l, w3h, w3l,
                                   linwh, linwl, wih0h, wih0l,
                                   whh0T, wih1T, whh1T);
  k_conv123<<<2048, 512, 0, stream>>>(X, w1, w2h, w2l, w3h, w3l, s3g);
  k_gemm_fx<<<128, 448, 0, stream>>>(s3g, linwh, linwl, wih0h, wih0l, xg0);
  k_lstm0<<<32, 512, 0, stream>>>(xg0, whh0T, lengths, hs1);
  k_xg1<<<256, 512, 0, stream>>>(hs1, wih1T, xg1);
  k_lstm1<<<32, 512, 0, stream>>>(xg1, whh1T, fc1, fc2, lengths, (float*)d_out);
}